// Round 3
// baseline (206.215 us; speedup 1.0000x reference)
//
#include <hip/hip_runtime.h>
#include <hip/hip_bf16.h>
#include <math.h>

typedef __hip_bfloat16 bf16;
typedef __attribute__((ext_vector_type(8))) short bf16x8;   // MFMA A/B frag (8 bf16)
typedef __attribute__((ext_vector_type(4))) float f32x4;    // MFMA C/D frag

#define NROW 4096
#define DIM  1024
#define APP  256
#define KQS  2048
#define SPLIT 3
#define SROWS 192

__device__ __forceinline__ unsigned short f2bu(float f) {
    bf16 h = __float2bfloat16(f);
    return *reinterpret_cast<unsigned short*>(&h);
}
__device__ __forceinline__ float bu2f(unsigned short u) {
    bf16 h; *reinterpret_cast<unsigned short*>(&h) = u;
    return __bfloat162float(h);
}
__device__ __forceinline__ unsigned pk2(float a, float b) {
    return (unsigned)f2bu(a) | ((unsigned)f2bu(b) << 16);
}
__device__ __forceinline__ void gload_lds16(const void* g, void* l) {
    __builtin_amdgcn_global_load_lds(
        (const __attribute__((address_space(1))) unsigned int*)g,
        (__attribute__((address_space(3))) unsigned int*)l, 16, 0, 0);
}

// ---------------- fp32 -> bf16 cast of x ----------------
__global__ __launch_bounds__(256) void cast_x_kernel(const float* __restrict__ x,
                                                     bf16* __restrict__ xb) {
    int idx = blockIdx.x * 256 + threadIdx.x;
    float4 v = ((const float4*)x)[idx];
    uint2 o; o.x = pk2(v.x, v.y); o.y = pk2(v.z, v.w);
    ((uint2*)xb)[idx] = o;
}

// ---------------- transpose+cast the 5 weight matrices ----------------
struct WPtrs { const float* s[5]; bf16* d[5]; };
__global__ __launch_bounds__(256) void tcast_kernel(WPtrs p) {
    __shared__ float T[64][65];
    const float* in = p.s[blockIdx.z];
    bf16* out = p.d[blockIdx.z];
    const int t = threadIdx.x;
    const int r0 = blockIdx.x * 64, c0 = blockIdx.y * 64;
    #pragma unroll
    for (int c = 0; c < 4; ++c) {
        int row = (t >> 4) + c * 16, col = (t & 15) * 4;
        float4 v = *(const float4*)(in + (size_t)(r0 + row) * 1024 + c0 + col);
        T[row][col] = v.x; T[row][col + 1] = v.y; T[row][col + 2] = v.z; T[row][col + 3] = v.w;
    }
    __syncthreads();
    #pragma unroll
    for (int c = 0; c < 4; ++c) {
        int orow = (t >> 4) + c * 16, ocol = (t & 15) * 4;
        uint2 o;
        o.x = pk2(T[ocol][orow], T[ocol + 1][orow]);
        o.y = pk2(T[ocol + 2][orow], T[ocol + 3][orow]);
        *(uint2*)(out + (size_t)(c0 + orow) * 1024 + r0 + ocol) = o;
    }
}

// ---------------- bf16 MFMA GEMM: C[M,N] = act(alpha*A@Bt^T + bias) ----------------
// A row-major [M,K]; Bt row-major [N,K]. Tile BMxBN, BK=64, 4 waves (2x2),
// XOR-swizzled LDS, global_load_lds with pre-swizzled source.
template <int BM, int BN>
__global__ __launch_bounds__(256) void gemm_bt(
    const bf16* __restrict__ A, const bf16* __restrict__ Bt, bf16* __restrict__ C,
    int M, int N, int K, float alpha, const float* __restrict__ bias, int relu)
{
    constexpr int WM = BM / 2, WN = BN / 2, AI = WM / 16, BJ = WN / 16;
    __shared__ bf16 As[BM * 64];
    __shared__ bf16 Bs[BN * 64];
    const int t = threadIdx.x, l = t & 63, w = t >> 6;
    const int wr = w >> 1, wc = w & 1;
    const int jl = l & 15, g = l >> 4;
    const int m0 = blockIdx.y * BM, n0 = blockIdx.x * BN;

    f32x4 acc[AI][BJ];
    #pragma unroll
    for (int i = 0; i < AI; ++i)
        #pragma unroll
        for (int j = 0; j < BJ; ++j) acc[i][j] = (f32x4){0.f, 0.f, 0.f, 0.f};

    for (int kk = 0; kk < K; kk += 64) {
        __syncthreads();
        #pragma unroll
        for (int c = 0; c < BM / 32; ++c) {
            int q = t + c * 256;
            int row = q >> 3;
            int kel = ((q & 7) ^ (row & 7)) << 3;
            gload_lds16(A + (size_t)(m0 + row) * K + kk + kel,
                        (char*)As + (c * 256 + w * 64) * 16);
        }
        #pragma unroll
        for (int c = 0; c < BN / 32; ++c) {
            int q = t + c * 256;
            int row = q >> 3;
            int kel = ((q & 7) ^ (row & 7)) << 3;
            gload_lds16(Bt + (size_t)(n0 + row) * K + kk + kel,
                        (char*)Bs + (c * 256 + w * 64) * 16);
        }
        __syncthreads();
        #pragma unroll
        for (int ks = 0; ks < 2; ++ks) {
            bf16x8 af[AI], bfr[BJ];
            #pragma unroll
            for (int i = 0; i < AI; ++i) {
                int ra = wr * WM + i * 16 + jl;
                af[i] = *(const bf16x8*)((char*)As + ra * 128 + ((ks * 64 + g * 16) ^ ((ra & 7) << 4)));
            }
            #pragma unroll
            for (int j = 0; j < BJ; ++j) {
                int rb = wc * WN + j * 16 + jl;
                bfr[j] = *(const bf16x8*)((char*)Bs + rb * 128 + ((ks * 64 + g * 16) ^ ((rb & 7) << 4)));
            }
            #pragma unroll
            for (int i = 0; i < AI; ++i)
                #pragma unroll
                for (int j = 0; j < BJ; ++j)
                    acc[i][j] = __builtin_amdgcn_mfma_f32_16x16x32_bf16(af[i], bfr[j], acc[i][j], 0, 0, 0);
        }
    }

    const int g4 = g * 4;
    #pragma unroll
    for (int j = 0; j < BJ; ++j) {
        int col = n0 + wc * WN + j * 16 + jl;
        float bv = bias ? bias[col] : 0.f;
        #pragma unroll
        for (int i = 0; i < AI; ++i) {
            int rowb = m0 + wr * WM + i * 16 + g4;
            #pragma unroll
            for (int r = 0; r < 4; ++r) {
                float vv = alpha * acc[i][j][r] + bv;
                if (relu) vv = fmaxf(vv, 0.f);
                C[(size_t)(rowb + r) * N + col] = __float2bfloat16(vv);
            }
        }
    }
}

// ---------------- banded attention, MFMA, split over i ----------------
// KQ: [4096][2048] bf16 (K | Q-unscaled). Vt: [1024][4096] bf16.
// Block (j0, split): 16 output rows j, band sub-window of SROWS=192 i-rows.
// Writes unnormalized partial Yp[split] (bf16) + per-column stats Ms/Ss.
__global__ __launch_bounds__(256) void attn_mfma(
    const bf16* __restrict__ KQ, const bf16* __restrict__ Vt,
    bf16* __restrict__ Yp, float* __restrict__ Ms, float* __restrict__ Ss)
{
    __shared__ bf16 Ks[16 * 1024];      // swizzled K rows (32 KB)
    __shared__ bf16 Pl[SROWS * 16];     // P in b-frag layout (6 KB)
    __shared__ float redm[4][16], reds[4][16];

    const int t = threadIdx.x, l = t & 63, w = t >> 6;
    const int g = l >> 4, jl = l & 15;
    const int j0 = blockIdx.x * 16;
    const int split = blockIdx.y;
    const int ib0 = j0 - 256 + split * SROWS;
    const bf16* Qb = KQ + 1024;

    // stage K rows j0..j0+15 (full depth) into LDS, XOR-swizzled
    #pragma unroll
    for (int c = 0; c < 8; ++c) {
        int q = t + c * 256;
        int row = q >> 7;
        int kb = (q & 127) << 4;
        uint4 v = *(const uint4*)((const char*)(KQ + (size_t)(j0 + row) * KQS) + kb);
        *(uint4*)((char*)Ks + row * 2048 + (kb ^ ((row & 7) << 4))) = v;
    }
    __syncthreads();

    // ---- S^T fragments: 3 per wave (12 per block = 192 i-rows) ----
    int irows[3];
    #pragma unroll
    for (int f = 0; f < 3; ++f) {
        int ir = ib0 + (w * 3 + f) * 16 + jl;
        irows[f] = min(max(ir, 0), NROW - 1);   // clamp addr; value masked later
    }

    f32x4 sacc[3];
    #pragma unroll
    for (int f = 0; f < 3; ++f) sacc[f] = (f32x4){0.f, 0.f, 0.f, 0.f};

    bf16x8 bcur = *(const bf16x8*)((const char*)Ks + jl * 2048 + ((g * 16) ^ ((jl & 7) << 4)));
    bf16x8 acur[3];
    #pragma unroll
    for (int f = 0; f < 3; ++f)
        acur[f] = *(const bf16x8*)(Qb + (size_t)irows[f] * KQS + g * 8);

    for (int kk = 0; kk < DIM - 32; kk += 32) {
        int k2 = kk + 32;
        bf16x8 bn = *(const bf16x8*)((const char*)Ks + jl * 2048 + ((k2 * 2 + g * 16) ^ ((jl & 7) << 4)));
        bf16x8 an[3];
        #pragma unroll
        for (int f = 0; f < 3; ++f)
            an[f] = *(const bf16x8*)(Qb + (size_t)irows[f] * KQS + k2 + g * 8);
        #pragma unroll
        for (int f = 0; f < 3; ++f)
            sacc[f] = __builtin_amdgcn_mfma_f32_16x16x32_bf16(acur[f], bcur, sacc[f], 0, 0, 0);
        bcur = bn;
        #pragma unroll
        for (int f = 0; f < 3; ++f) acur[f] = an[f];
    }
    #pragma unroll
    for (int f = 0; f < 3; ++f)
        sacc[f] = __builtin_amdgcn_mfma_f32_16x16x32_bf16(acur[f], bcur, sacc[f], 0, 0, 0);

    // ---- masked per-split softmax stats over i (column j = j0+jl lane-local) ----
    float mv[3][4];
    float mx = -3e38f;
    #pragma unroll
    for (int f = 0; f < 3; ++f) {
        #pragma unroll
        for (int r = 0; r < 4; ++r) {
            int ioff = (w * 3 + f) * 16 + g * 4 + r;
            int i = ib0 + ioff;
            int dd = i - (j0 + jl);
            bool ok = (i >= 0) && (i < NROW) && (dd >= -APP) && (dd <= APP);
            float vv = ok ? sacc[f][r] * 0.06f : -3e38f;   // fold Q scale
            mv[f][r] = vv;
            mx = fmaxf(mx, vv);
        }
    }
    mx = fmaxf(mx, __shfl_xor(mx, 16));
    mx = fmaxf(mx, __shfl_xor(mx, 32));
    if (l < 16) redm[w][l] = mx;
    __syncthreads();
    float M = fmaxf(fmaxf(redm[0][jl], redm[1][jl]), fmaxf(redm[2][jl], redm[3][jl]));
    float sum = 0.f;
    #pragma unroll
    for (int f = 0; f < 3; ++f)
        #pragma unroll
        for (int r = 0; r < 4; ++r) {
            float e = __expf(mv[f][r] - M);
            mv[f][r] = e;
            sum += e;
        }
    sum += __shfl_xor(sum, 16);
    sum += __shfl_xor(sum, 32);
    if (l < 16) reds[w][l] = sum;
    __syncthreads();
    float S = reds[0][jl] + reds[1][jl] + reds[2][jl] + reds[3][jl];
    if (w == 0 && l < 16) {
        Ms[split * NROW + j0 + l] = M;
        Ss[split * NROW + j0 + l] = S;
    }
    // store unnormalized P (<=1) in b-frag layout
    #pragma unroll
    for (int f = 0; f < 3; ++f) {
        uint2 p;
        p.x = pk2(mv[f][0], mv[f][1]);
        p.y = pk2(mv[f][2], mv[f][3]);
        int chunk = (w * 3 + f) * 2 + (g >> 1);
        *(uint2*)((char*)Pl + chunk * 256 + jl * 16 + (g & 1) * 8) = p;
    }
    __syncthreads();

    // ---- partial Y^T = Vt(band slice) @ P : wave owns 256 d, 6 k-steps ----
    bf16* Yout = Yp + (size_t)split * NROW * DIM;
    #pragma unroll
    for (int half = 0; half < 2; ++half) {
        const int db = w * 256 + half * 128;
        f32x4 yacc[8];
        #pragma unroll
        for (int df = 0; df < 8; ++df) yacc[df] = (f32x4){0.f, 0.f, 0.f, 0.f};

        bf16x8 pcur = *(const bf16x8*)((const char*)Pl + g * 256 + jl * 16);
        bf16x8 vcur[8];
        #pragma unroll
        for (int df = 0; df < 8; ++df)
            vcur[df] = *(const bf16x8*)(Vt + (ptrdiff_t)(db + df * 16 + jl) * NROW + ib0 + g * 8);

        for (int st = 0; st < 5; ++st) {
            bf16x8 pn = *(const bf16x8*)((const char*)Pl + ((st + 1) * 4 + g) * 256 + jl * 16);
            bf16x8 vn[8];
            #pragma unroll
            for (int df = 0; df < 8; ++df)
                vn[df] = *(const bf16x8*)(Vt + (ptrdiff_t)(db + df * 16 + jl) * NROW + ib0 + (st + 1) * 32 + g * 8);
            #pragma unroll
            for (int df = 0; df < 8; ++df)
                yacc[df] = __builtin_amdgcn_mfma_f32_16x16x32_bf16(vcur[df], pcur, yacc[df], 0, 0, 0);
            pcur = pn;
            #pragma unroll
            for (int df = 0; df < 8; ++df) vcur[df] = vn[df];
        }
        #pragma unroll
        for (int df = 0; df < 8; ++df)
            yacc[df] = __builtin_amdgcn_mfma_f32_16x16x32_bf16(vcur[df], pcur, yacc[df], 0, 0, 0);

        #pragma unroll
        for (int df = 0; df < 8; ++df) {
            int d = db + df * 16 + g * 4;
            uint2 o;
            o.x = pk2(yacc[df][0], yacc[df][1]);
            o.y = pk2(yacc[df][2], yacc[df][3]);
            *(uint2*)(Yout + (size_t)(j0 + jl) * DIM + d) = o;
        }
    }
}

// ---------------- combine the 3 split partials ----------------
__global__ __launch_bounds__(256) void attn_combine(
    const bf16* __restrict__ Yp, const float* __restrict__ Ms,
    const float* __restrict__ Ss, bf16* __restrict__ Y)
{
    const int j = blockIdx.x, t = threadIdx.x;
    float m0 = Ms[j], m1 = Ms[NROW + j], m2 = Ms[2 * NROW + j];
    float M = fmaxf(fmaxf(m0, m1), m2);
    float e0 = __expf(m0 - M), e1 = __expf(m1 - M), e2 = __expf(m2 - M);
    float inv = 1.f / (Ss[j] * e0 + Ss[NROW + j] * e1 + Ss[2 * NROW + j] * e2);
    float s0 = e0 * inv, s1 = e1 * inv, s2 = e2 * inv;
    const size_t base = (size_t)j * DIM;
    const size_t NM = (size_t)NROW * DIM;
    uint2 a = ((const uint2*)(Yp + base))[t];
    uint2 b = ((const uint2*)(Yp + NM + base))[t];
    uint2 c = ((const uint2*)(Yp + 2 * NM + base))[t];
    float r0 = s0 * bu2f((unsigned short)(a.x & 0xffff)) + s1 * bu2f((unsigned short)(b.x & 0xffff)) + s2 * bu2f((unsigned short)(c.x & 0xffff));
    float r1 = s0 * bu2f((unsigned short)(a.x >> 16))    + s1 * bu2f((unsigned short)(b.x >> 16))    + s2 * bu2f((unsigned short)(c.x >> 16));
    float r2 = s0 * bu2f((unsigned short)(a.y & 0xffff)) + s1 * bu2f((unsigned short)(b.y & 0xffff)) + s2 * bu2f((unsigned short)(c.y & 0xffff));
    float r3 = s0 * bu2f((unsigned short)(a.y >> 16))    + s1 * bu2f((unsigned short)(b.y >> 16))    + s2 * bu2f((unsigned short)(c.y >> 16));
    uint2 o; o.x = pk2(r0, r1); o.y = pk2(r2, r3);
    ((uint2*)(Y + base))[t] = o;
}

// ---------------- LayerNorm: O = LN(T (+X)) * g + b ----------------
__global__ __launch_bounds__(256) void ln_kernel(
    const bf16* __restrict__ T, const float* __restrict__ X,
    const float* __restrict__ g, const float* __restrict__ b, bf16* __restrict__ O)
{
    __shared__ float red1[4], red2[4];
    const int r = blockIdx.x, t = threadIdx.x, lane = t & 63, w = t >> 6;
    ushort4 tv = ((const ushort4*)(T + (size_t)r * DIM))[t];
    float v0 = bu2f(tv.x), v1 = bu2f(tv.y), v2 = bu2f(tv.z), v3 = bu2f(tv.w);
    if (X) {
        float4 xv = ((const float4*)(X + (size_t)r * DIM))[t];
        v0 += xv.x; v1 += xv.y; v2 += xv.z; v3 += xv.w;
    }
    float s = v0 + v1 + v2 + v3;
    #pragma unroll
    for (int off = 32; off > 0; off >>= 1) s += __shfl_xor(s, off);
    if (lane == 0) red1[w] = s;
    __syncthreads();
    float mu = (red1[0] + red1[1] + red1[2] + red1[3]) * (1.f / DIM);
    float d0 = v0 - mu, d1 = v1 - mu, d2 = v2 - mu, d3 = v3 - mu;
    float s2 = d0 * d0 + d1 * d1 + d2 * d2 + d3 * d3;
    #pragma unroll
    for (int off = 32; off > 0; off >>= 1) s2 += __shfl_xor(s2, off);
    if (lane == 0) red2[w] = s2;
    __syncthreads();
    float var = (red2[0] + red2[1] + red2[2] + red2[3]) * (1.f / DIM);
    float rstd = rsqrtf(var + 1e-3f);
    float4 gv = ((const float4*)g)[t];
    float4 bv = ((const float4*)b)[t];
    uint2 o;
    o.x = pk2(d0 * rstd * gv.x + bv.x, d1 * rstd * gv.y + bv.y);
    o.y = pk2(d2 * rstd * gv.z + bv.z, d3 * rstd * gv.w + bv.w);
    ((uint2*)(O + (size_t)r * DIM))[t] = o;
}

// ---------------- out[r] = sigmoid(Y[r].wkd + bkd) ----------------
__global__ __launch_bounds__(256) void final_kernel(
    const bf16* __restrict__ Y, const float* __restrict__ wkd,
    const float* __restrict__ bkd, float* __restrict__ out)
{
    const int lane = threadIdx.x & 63, w = threadIdx.x >> 6;
    const int r = blockIdx.x * 4 + w;
    const bf16* yr = Y + (size_t)r * DIM;
    float s = 0.f;
    #pragma unroll
    for (int c = 0; c < 4; ++c) {
        ushort4 yv = ((const ushort4*)yr)[lane * 4 + c];
        float4 wv = ((const float4*)wkd)[lane * 4 + c];
        s += bu2f(yv.x) * wv.x + bu2f(yv.y) * wv.y + bu2f(yv.z) * wv.z + bu2f(yv.w) * wv.w;
    }
    #pragma unroll
    for (int off = 32; off > 0; off >>= 1) s += __shfl_xor(s, off);
    if (lane == 0) out[r] = 1.f / (1.f + __expf(-(s + bkd[0])));
}

extern "C" void kernel_launch(void* const* d_in, const int* in_sizes, int n_in,
                              void* d_out, int out_size, void* d_ws, size_t ws_size,
                              hipStream_t stream) {
    const float* x    = (const float*)d_in[0];
    const float* wk   = (const float*)d_in[1];
    const float* wq   = (const float*)d_in[2];
    const float* wv   = (const float*)d_in[3];
    const float* wo   = (const float*)d_in[4];
    const float* wka  = (const float*)d_in[5];
    const float* bka  = (const float*)d_in[6];
    const float* wkd  = (const float*)d_in[7];
    const float* bkd  = (const float*)d_in[8];
    const float* g_y  = (const float*)d_in[9];
    const float* b_y  = (const float*)d_in[10];
    const float* g_ka = (const float*)d_in[11];
    const float* b_ka = (const float*)d_in[12];
    float* out = (float*)d_out;

    char* ws = (char*)d_ws;
    const size_t MB = 1u << 20;
    const size_t NM = (size_t)NROW * DIM;
    // persistent: woT, wkaT, fKQ, fVt, Yp. Early-dead overlays inside Yp region.
    bf16* woT  = (bf16*)(ws);             // 2 MB
    bf16* wkaT = (bf16*)(ws + 2 * MB);    // 2 MB
    bf16* fKQ  = (bf16*)(ws + 4 * MB);    // 16 MB [4096][2048]
    bf16* fVt  = (bf16*)(ws + 20 * MB);   // 8 MB  [1024][4096]
    bf16* Yp   = (bf16*)(ws + 28 * MB);   // 24 MB [3][4096][1024]
    bf16* xb   = (bf16*)(ws + 28 * MB);   // 8 MB overlay (dead before attn)
    bf16* wkT  = (bf16*)(ws + 36 * MB);   // 2 MB overlay (wkT+wqT contiguous)
    bf16* wqT  = (bf16*)(ws + 38 * MB);   // 2 MB overlay
    bf16* wvT  = (bf16*)(ws + 40 * MB);   // 2 MB overlay
    float* Ms  = (float*)(ws + 52 * MB);  // 48 KB
    float* Ss  = (float*)(ws + 52 * MB + 64 * 1024);
    bf16* fY   = Yp;                      // combine output aliases part 0
    bf16* fT   = fKQ;                     // post-attn temps reuse fKQ
    bf16* fL1  = fKQ + NM;

    cast_x_kernel<<<NROW * DIM / 4 / 256, 256, 0, stream>>>(x, xb);
    WPtrs wp;
    wp.s[0] = wk;  wp.s[1] = wq;  wp.s[2] = wv;  wp.s[3] = wo;  wp.s[4] = wka;
    wp.d[0] = wkT; wp.d[1] = wqT; wp.d[2] = wvT; wp.d[3] = woT; wp.d[4] = wkaT;
    tcast_kernel<<<dim3(16, 16, 5), 256, 0, stream>>>(wp);

    // fused K|Q GEMM: [4096][2048] = xb @ [wkT;wqT]^T
    gemm_bt<128, 128><<<dim3(2048 / 128, NROW / 128), 256, 0, stream>>>(
        xb, wkT, fKQ, NROW, KQS, DIM, 1.f, nullptr, 0);
    // Vt = wvT @ xb^T : [1024][4096]
    gemm_bt<64, 128><<<dim3(NROW / 128, DIM / 64), 256, 0, stream>>>(
        wvT, xb, fVt, DIM, NROW, DIM, 1.f, nullptr, 0);

    attn_mfma<<<dim3(NROW / 16, SPLIT), 256, 0, stream>>>(fKQ, fVt, Yp, Ms, Ss);
    attn_combine<<<NROW, 256, 0, stream>>>(Yp, Ms, Ss, fY);

    gemm_bt<128, 64><<<dim3(DIM / 64, NROW / 128), 256, 0, stream>>>(
        fY, woT, fT, NROW, DIM, DIM, 1.f, nullptr, 0);
    ln_kernel<<<NROW, 256, 0, stream>>>(fT, x, g_y, b_y, fL1);
    gemm_bt<128, 64><<<dim3(DIM / 64, NROW / 128), 256, 0, stream>>>(
        fL1, wkaT, fVt, NROW, DIM, DIM, 1.f, bka, 1);
    ln_kernel<<<NROW, 256, 0, stream>>>(fVt, nullptr, g_ka, b_ka, fT);
    final_kernel<<<NROW / 4, 256, 0, stream>>>(fT, wkd, bkd, out);
}

// Round 4
// 148.023 us; speedup vs baseline: 1.3931x; 1.3931x over previous
//
#include <hip/hip_runtime.h>
#include <hip/hip_bf16.h>
#include <math.h>

typedef __hip_bfloat16 bf16;
typedef __attribute__((ext_vector_type(8))) short bf16x8;   // MFMA A/B frag (8 bf16)
typedef __attribute__((ext_vector_type(4))) float f32x4;    // MFMA C/D frag

#define NROW 4096
#define DIM  1024
#define APP  256
#define KQS  2048
#define WIN  640          // band window per 128-row j-tile: 128 + 2*APP
#define VTPW 4608         // padded Vt width: 256 | 4096 | 256

__device__ __forceinline__ unsigned short f2bu(float f) {
    bf16 h = __float2bfloat16(f);
    return *reinterpret_cast<unsigned short*>(&h);
}
__device__ __forceinline__ float bu2f(unsigned short u) {
    bf16 h; *reinterpret_cast<unsigned short*>(&h) = u;
    return __bfloat162float(h);
}
__device__ __forceinline__ unsigned pk2(float a, float b) {
    return (unsigned)f2bu(a) | ((unsigned)f2bu(b) << 16);
}
__device__ __forceinline__ void gload_lds16(const void* g, void* l) {
    __builtin_amdgcn_global_load_lds(
        (const __attribute__((address_space(1))) unsigned int*)g,
        (__attribute__((address_space(3))) unsigned int*)l, 16, 0, 0);
}

// ---------------- fp32 -> bf16 cast of x ----------------
__global__ __launch_bounds__(256) void cast_x_kernel(const float* __restrict__ x,
                                                     bf16* __restrict__ xb) {
    int idx = blockIdx.x * 256 + threadIdx.x;
    float4 v = ((const float4*)x)[idx];
    uint2 o; o.x = pk2(v.x, v.y); o.y = pk2(v.z, v.w);
    ((uint2*)xb)[idx] = o;
}

// ---------------- transpose+cast the 5 weight matrices ----------------
struct WPtrs { const float* s[5]; bf16* d[5]; };
__global__ __launch_bounds__(256) void tcast_kernel(WPtrs p) {
    __shared__ float T[64][65];
    const float* in = p.s[blockIdx.z];
    bf16* out = p.d[blockIdx.z];
    const int t = threadIdx.x;
    const int r0 = blockIdx.x * 64, c0 = blockIdx.y * 64;
    #pragma unroll
    for (int c = 0; c < 4; ++c) {
        int row = (t >> 4) + c * 16, col = (t & 15) * 4;
        float4 v = *(const float4*)(in + (size_t)(r0 + row) * 1024 + c0 + col);
        T[row][col] = v.x; T[row][col + 1] = v.y; T[row][col + 2] = v.z; T[row][col + 3] = v.w;
    }
    __syncthreads();
    #pragma unroll
    for (int c = 0; c < 4; ++c) {
        int orow = (t >> 4) + c * 16, ocol = (t & 15) * 4;
        uint2 o;
        o.x = pk2(T[ocol][orow], T[ocol + 1][orow]);
        o.y = pk2(T[ocol + 2][orow], T[ocol + 3][orow]);
        *(uint2*)(out + (size_t)(c0 + orow) * 1024 + r0 + ocol) = o;
    }
}

// ---------------- bf16 MFMA GEMM: C[M,N] = act(alpha*A@Bt^T + bias) ----------------
// A row-major [M,K] stride lda; Bt row-major [N,K] stride ldb; C stride ldc.
// pv!=0: Bt base += (m0>>7)*128 (banded PV: per-128-j-tile column offset into Vtp).
template <int BM, int BN>
__global__ __launch_bounds__(256) void gemm_bt(
    const bf16* __restrict__ A, int lda, const bf16* __restrict__ Bt, int ldb,
    bf16* __restrict__ C, int ldc, int K,
    float alpha, const float* __restrict__ bias, int relu, int pv)
{
    constexpr int WM = BM / 2, WN = BN / 2, AI = WM / 16, BJ = WN / 16;
    __shared__ bf16 As[BM * 64];
    __shared__ bf16 Bs[BN * 64];
    const int t = threadIdx.x, l = t & 63, w = t >> 6;
    const int wr = w >> 1, wc = w & 1;
    const int jl = l & 15, g = l >> 4;
    const int m0 = blockIdx.y * BM, n0 = blockIdx.x * BN;
    const bf16* Btb = pv ? (Bt + (size_t)(m0 >> 7) * 128) : Bt;

    f32x4 acc[AI][BJ];
    #pragma unroll
    for (int i = 0; i < AI; ++i)
        #pragma unroll
        for (int j = 0; j < BJ; ++j) acc[i][j] = (f32x4){0.f, 0.f, 0.f, 0.f};

    for (int kk = 0; kk < K; kk += 64) {
        __syncthreads();
        #pragma unroll
        for (int c = 0; c < BM / 32; ++c) {
            int q = t + c * 256;
            int row = q >> 3;
            int kel = ((q & 7) ^ (row & 7)) << 3;
            gload_lds16(A + (size_t)(m0 + row) * lda + kk + kel,
                        (char*)As + (c * 256 + w * 64) * 16);
        }
        #pragma unroll
        for (int c = 0; c < BN / 32; ++c) {
            int q = t + c * 256;
            int row = q >> 3;
            int kel = ((q & 7) ^ (row & 7)) << 3;
            gload_lds16(Btb + (size_t)(n0 + row) * ldb + kk + kel,
                        (char*)Bs + (c * 256 + w * 64) * 16);
        }
        __syncthreads();
        #pragma unroll
        for (int ks = 0; ks < 2; ++ks) {
            bf16x8 af[AI], bfr[BJ];
            #pragma unroll
            for (int i = 0; i < AI; ++i) {
                int ra = wr * WM + i * 16 + jl;
                af[i] = *(const bf16x8*)((char*)As + ra * 128 + ((ks * 64 + g * 16) ^ ((ra & 7) << 4)));
            }
            #pragma unroll
            for (int j = 0; j < BJ; ++j) {
                int rb = wc * WN + j * 16 + jl;
                bfr[j] = *(const bf16x8*)((char*)Bs + rb * 128 + ((ks * 64 + g * 16) ^ ((rb & 7) << 4)));
            }
            #pragma unroll
            for (int i = 0; i < AI; ++i)
                #pragma unroll
                for (int j = 0; j < BJ; ++j)
                    acc[i][j] = __builtin_amdgcn_mfma_f32_16x16x32_bf16(af[i], bfr[j], acc[i][j], 0, 0, 0);
        }
    }

    const int g4 = g * 4;
    #pragma unroll
    for (int j = 0; j < BJ; ++j) {
        int col = n0 + wc * WN + j * 16 + jl;
        float bv = bias ? bias[col] : 0.f;
        #pragma unroll
        for (int i = 0; i < AI; ++i) {
            int rowb = m0 + wr * WM + i * 16 + g4;
            #pragma unroll
            for (int r = 0; r < 4; ++r) {
                float vv = alpha * acc[i][j][r] + bv;
                if (relu) vv = fmaxf(vv, 0.f);
                C[(size_t)(rowb + r) * ldc + col] = __float2bfloat16(vv);
            }
        }
    }
}

// ---------------- banded score GEMM: St[j][iw] = 0.06 * Q[w0+iw] . K[j] ----------------
// Block: (iw-chunk of 64) x (j-tile of 128). Q rows clamped (masked later by position).
__global__ __launch_bounds__(256) void score_gemm(const bf16* __restrict__ KQ,
                                                  bf16* __restrict__ St)
{
    constexpr int WM = 32, WN = 64, AI = 2, BJ = 4;
    __shared__ bf16 As[64 * 64];
    __shared__ bf16 Bs[128 * 64];
    const int t = threadIdx.x, l = t & 63, w = t >> 6;
    const int wr = w >> 1, wc = w & 1;
    const int jl = l & 15, g = l >> 4;
    const int tt = blockIdx.y;              // j-tile 0..31
    const int c0 = blockIdx.x * 64;         // iw chunk base
    const int w0 = tt * 128 - 2 * APP / 2 * 2;  // tt*128 - 512/2... keep explicit below
    const int wbase = tt * 128 - 2 * APP;   // unused guard
    (void)w0; (void)wbase;
    const int win0 = tt * 128 - APP;        // hmm: window start = tt*128 - 256
    const bf16* Qb = KQ + 1024;
    const bf16* Kb = KQ + (size_t)tt * 128 * KQS;

    f32x4 acc[AI][BJ];
    #pragma unroll
    for (int i = 0; i < AI; ++i)
        #pragma unroll
        for (int j = 0; j < BJ; ++j) acc[i][j] = (f32x4){0.f, 0.f, 0.f, 0.f};

    for (int kk = 0; kk < DIM; kk += 64) {
        __syncthreads();
        #pragma unroll
        for (int c = 0; c < 2; ++c) {
            int q = t + c * 256;
            int row = q >> 3;
            int kel = ((q & 7) ^ (row & 7)) << 3;
            int rg = win0 + c0 + row;
            rg = min(max(rg, 0), NROW - 1);
            gload_lds16(Qb + (size_t)rg * KQS + kk + kel,
                        (char*)As + (c * 256 + w * 64) * 16);
        }
        #pragma unroll
        for (int c = 0; c < 4; ++c) {
            int q = t + c * 256;
            int row = q >> 3;
            int kel = ((q & 7) ^ (row & 7)) << 3;
            gload_lds16(Kb + (size_t)row * KQS + kk + kel,
                        (char*)Bs + (c * 256 + w * 64) * 16);
        }
        __syncthreads();
        #pragma unroll
        for (int ks = 0; ks < 2; ++ks) {
            bf16x8 af[AI], bfr[BJ];
            #pragma unroll
            for (int i = 0; i < AI; ++i) {
                int ra = wr * WM + i * 16 + jl;
                af[i] = *(const bf16x8*)((char*)As + ra * 128 + ((ks * 64 + g * 16) ^ ((ra & 7) << 4)));
            }
            #pragma unroll
            for (int j = 0; j < BJ; ++j) {
                int rb = wc * WN + j * 16 + jl;
                bfr[j] = *(const bf16x8*)((char*)Bs + rb * 128 + ((ks * 64 + g * 16) ^ ((rb & 7) << 4)));
            }
            #pragma unroll
            for (int i = 0; i < AI; ++i)
                #pragma unroll
                for (int j = 0; j < BJ; ++j)
                    acc[i][j] = __builtin_amdgcn_mfma_f32_16x16x32_bf16(af[i], bfr[j], acc[i][j], 0, 0, 0);
        }
    }

    // epilogue: St[(tt*128 + j_local)*WIN + c0 + iw_local] = 0.06*acc  (r contiguous in iw)
    const int g4 = g * 4;
    #pragma unroll
    for (int j = 0; j < BJ; ++j) {
        int coll = wc * WN + j * 16 + jl;
        bf16* strow = St + (size_t)(tt * 128 + coll) * WIN;
        #pragma unroll
        for (int i = 0; i < AI; ++i) {
            int iwb = c0 + wr * WM + i * 16 + g4;
            #pragma unroll
            for (int r = 0; r < 4; ++r)
                strow[iwb + r] = __float2bfloat16(0.06f * acc[i][j][r]);
        }
    }
}

// ---------------- masked row softmax over the 640-wide band window ----------------
// Row j (tile tt=j>>7, jt=j&127): valid iw in [max(jt,256-128tt), min(jt+512,4351-128tt)].
__global__ __launch_bounds__(256) void softmax_band(bf16* __restrict__ St)
{
    const int w = threadIdx.x >> 6, l = threadIdx.x & 63;
    const int j = blockIdx.x * 4 + w;
    const int tt = j >> 7, jt = j & 127;
    unsigned* row = (unsigned*)(St + (size_t)j * WIN);
    const int lo = max(jt, 256 - 128 * tt);
    const int hi = min(jt + 512, 4351 - 128 * tt);
    unsigned u[5]; float v[10];
    #pragma unroll
    for (int c = 0; c < 5; ++c) u[c] = row[l + 64 * c];
    float m = -3e38f;
    #pragma unroll
    for (int c = 0; c < 5; ++c) {
        int iw = 2 * (l + 64 * c);
        v[2 * c]     = (iw >= lo && iw <= hi)         ? bu2f((unsigned short)(u[c] & 0xffff)) : -3e38f;
        v[2 * c + 1] = (iw + 1 >= lo && iw + 1 <= hi) ? bu2f((unsigned short)(u[c] >> 16))    : -3e38f;
        m = fmaxf(m, fmaxf(v[2 * c], v[2 * c + 1]));
    }
    #pragma unroll
    for (int off = 32; off > 0; off >>= 1) m = fmaxf(m, __shfl_xor(m, off));
    float s = 0.f;
    #pragma unroll
    for (int c = 0; c < 10; ++c) {
        float e = (v[c] > -1e37f) ? __expf(v[c] - m) : 0.f;
        v[c] = e; s += e;
    }
    #pragma unroll
    for (int off = 32; off > 0; off >>= 1) s += __shfl_xor(s, off);
    const float inv = 1.f / s;
    #pragma unroll
    for (int c = 0; c < 5; ++c)
        row[l + 64 * c] = pk2(v[2 * c] * inv, v[2 * c + 1] * inv);
}

// ---------------- LayerNorm: O = LN(T (+X)) * g + b ----------------
__global__ __launch_bounds__(256) void ln_kernel(
    const bf16* __restrict__ T, const float* __restrict__ X,
    const float* __restrict__ g, const float* __restrict__ b, bf16* __restrict__ O)
{
    __shared__ float red1[4], red2[4];
    const int r = blockIdx.x, t = threadIdx.x, lane = t & 63, w = t >> 6;
    ushort4 tv = ((const ushort4*)(T + (size_t)r * DIM))[t];
    float v0 = bu2f(tv.x), v1 = bu2f(tv.y), v2 = bu2f(tv.z), v3 = bu2f(tv.w);
    if (X) {
        float4 xv = ((const float4*)(X + (size_t)r * DIM))[t];
        v0 += xv.x; v1 += xv.y; v2 += xv.z; v3 += xv.w;
    }
    float s = v0 + v1 + v2 + v3;
    #pragma unroll
    for (int off = 32; off > 0; off >>= 1) s += __shfl_xor(s, off);
    if (lane == 0) red1[w] = s;
    __syncthreads();
    float mu = (red1[0] + red1[1] + red1[2] + red1[3]) * (1.f / DIM);
    float d0 = v0 - mu, d1 = v1 - mu, d2 = v2 - mu, d3 = v3 - mu;
    float s2 = d0 * d0 + d1 * d1 + d2 * d2 + d3 * d3;
    #pragma unroll
    for (int off = 32; off > 0; off >>= 1) s2 += __shfl_xor(s2, off);
    if (lane == 0) red2[w] = s2;
    __syncthreads();
    float var = (red2[0] + red2[1] + red2[2] + red2[3]) * (1.f / DIM);
    float rstd = rsqrtf(var + 1e-3f);
    float4 gv = ((const float4*)g)[t];
    float4 bv = ((const float4*)b)[t];
    uint2 o;
    o.x = pk2(d0 * rstd * gv.x + bv.x, d1 * rstd * gv.y + bv.y);
    o.y = pk2(d2 * rstd * gv.z + bv.z, d3 * rstd * gv.w + bv.w);
    ((uint2*)(O + (size_t)r * DIM))[t] = o;
}

// ---------------- out[r] = sigmoid(Y[r].wkd + bkd) ----------------
__global__ __launch_bounds__(256) void final_kernel(
    const bf16* __restrict__ Y, const float* __restrict__ wkd,
    const float* __restrict__ bkd, float* __restrict__ out)
{
    const int lane = threadIdx.x & 63, w = threadIdx.x >> 6;
    const int r = blockIdx.x * 4 + w;
    const bf16* yr = Y + (size_t)r * DIM;
    float s = 0.f;
    #pragma unroll
    for (int c = 0; c < 4; ++c) {
        ushort4 yv = ((const ushort4*)yr)[lane * 4 + c];
        float4 wv = ((const float4*)wkd)[lane * 4 + c];
        s += bu2f(yv.x) * wv.x + bu2f(yv.y) * wv.y + bu2f(yv.z) * wv.z + bu2f(yv.w) * wv.w;
    }
    #pragma unroll
    for (int off = 32; off > 0; off >>= 1) s += __shfl_xor(s, off);
    if (lane == 0) out[r] = 1.f / (1.f + __expf(-(s + bkd[0])));
}

extern "C" void kernel_launch(void* const* d_in, const int* in_sizes, int n_in,
                              void* d_out, int out_size, void* d_ws, size_t ws_size,
                              hipStream_t stream) {
    const float* x    = (const float*)d_in[0];
    const float* wk   = (const float*)d_in[1];
    const float* wq   = (const float*)d_in[2];
    const float* wv   = (const float*)d_in[3];
    const float* wo   = (const float*)d_in[4];
    const float* wka  = (const float*)d_in[5];
    const float* bka  = (const float*)d_in[6];
    const float* wkd  = (const float*)d_in[7];
    const float* bkd  = (const float*)d_in[8];
    const float* g_y  = (const float*)d_in[9];
    const float* b_y  = (const float*)d_in[10];
    const float* g_ka = (const float*)d_in[11];
    const float* b_ka = (const float*)d_in[12];
    float* out = (float*)d_out;

    char* ws = (char*)d_ws;
    const size_t MB = 1u << 20;
    const size_t NM = (size_t)NROW * DIM;
    // layout (peak 52 MB):
    bf16* woT  = (bf16*)(ws);              // 2 MB
    bf16* wkaT = (bf16*)(ws + 2 * MB);     // 2 MB
    bf16* fKQ  = (bf16*)(ws + 4 * MB);     // 16 MB [4096][2048]
    bf16* Vtp  = (bf16*)(ws + 20 * MB);    // 9 MB  [1024][4608] zero-padded
    bf16* St   = (bf16*)(ws + 30 * MB);    // 5 MB  [4096][640]
    bf16* fY   = (bf16*)(ws + 36 * MB);    // 8 MB  [4096][1024] (PV out)
    bf16* wkT  = (bf16*)(ws + 36 * MB);    // overlay: dead before PV writes fY
    bf16* wqT  = (bf16*)(ws + 38 * MB);    //   (wkT|wqT contiguous 2048 rows)
    bf16* wvT  = (bf16*)(ws + 40 * MB);    // overlay
    bf16* xb   = (bf16*)(ws + 44 * MB);    // 8 MB
    bf16* fT   = fKQ;                      // wo out   (KQ dead after score)
    bf16* fL1  = fKQ + NM;                 // ln1 out
    bf16* fRel = Vtp;                      // wka out  (Vtp dead after PV)
    bf16* fT2  = fY;                       // ln2 out  (fY dead after wo)

    hipMemsetAsync(Vtp, 0, (size_t)DIM * VTPW * sizeof(bf16), stream);
    cast_x_kernel<<<NROW * DIM / 4 / 256, 256, 0, stream>>>(x, xb);
    WPtrs wp;
    wp.s[0] = wk;  wp.s[1] = wq;  wp.s[2] = wv;  wp.s[3] = wo;  wp.s[4] = wka;
    wp.d[0] = wkT; wp.d[1] = wqT; wp.d[2] = wvT; wp.d[3] = woT; wp.d[4] = wkaT;
    tcast_kernel<<<dim3(16, 16, 5), 256, 0, stream>>>(wp);

    // KQ = xb @ [wkT;wqT]^T : [4096][2048]
    gemm_bt<128, 128><<<dim3(16, 32), 256, 0, stream>>>(
        xb, DIM, wkT, DIM, fKQ, KQS, DIM, 1.f, nullptr, 0, 0);
    // Vt (padded) = wvT @ xb^T : [1024][4096] into Vtp[:, 256:4352]
    gemm_bt<64, 128><<<dim3(32, 16), 256, 0, stream>>>(
        wvT, DIM, xb, DIM, Vtp + 2 * APP / 2 * 1, VTPW, DIM, 1.f, nullptr, 0, 0);

    score_gemm<<<dim3(WIN / 64, NROW / 128), 256, 0, stream>>>(fKQ, St);
    softmax_band<<<NROW / 4, 256, 0, stream>>>(St);
    // Y = St @ V(band) : gemm over K=640 with per-j-tile Vtp column offset
    gemm_bt<64, 128><<<dim3(8, 64), 256, 0, stream>>>(
        St, WIN, Vtp, VTPW, fY, DIM, WIN, 1.f, nullptr, 0, 1);

    gemm_bt<128, 64><<<dim3(16, 32), 256, 0, stream>>>(
        fY, DIM, woT, DIM, fT, DIM, DIM, 1.f, nullptr, 0, 0);
    ln_kernel<<<NROW, 256, 0, stream>>>(fT, x, g_y, b_y, fL1);
    gemm_bt<128, 64><<<dim3(16, 32), 256, 0, stream>>>(
        fL1, DIM, wkaT, DIM, fRel, DIM, DIM, 1.f, bka, 1, 0);
    ln_kernel<<<NROW, 256, 0, stream>>>(fRel, nullptr, g_ka, b_ka, fT2);
    final_kernel<<<NROW / 4, 256, 0, stream>>>(fT2, wkd, bkd, out);
}

// Round 6
// 147.128 us; speedup vs baseline: 1.4016x; 1.0061x over previous
//
#include <hip/hip_runtime.h>
#include <hip/hip_bf16.h>
#include <math.h>

typedef __hip_bfloat16 bf16;
typedef __attribute__((ext_vector_type(8))) short bf16x8;   // MFMA A/B frag (8 bf16)
typedef __attribute__((ext_vector_type(4))) float f32x4;    // MFMA C/D frag

#define NROW 4096
#define DIM  1024
#define APP  256
#define KQS  2048
#define WIN  640          // band window per 128-row j-tile: 128 + 2*APP
#define VTPW 4608         // padded Vt width: 256 | 4096 | 256

__device__ __forceinline__ unsigned short f2bu(float f) {
    bf16 h = __float2bfloat16(f);
    return *reinterpret_cast<unsigned short*>(&h);
}
__device__ __forceinline__ float bu2f(unsigned short u) {
    bf16 h; *reinterpret_cast<unsigned short*>(&h) = u;
    return __bfloat162float(h);
}
__device__ __forceinline__ unsigned pk2(float a, float b) {
    return (unsigned)f2bu(a) | ((unsigned)f2bu(b) << 16);
}
__device__ __forceinline__ void gload_lds16(const void* g, void* l) {
    __builtin_amdgcn_global_load_lds(
        (const __attribute__((address_space(1))) unsigned int*)g,
        (__attribute__((address_space(3))) unsigned int*)l, 16, 0, 0);
}

// ---------------- zero only the pad strips of Vtp (cols 0..255 and 4352..4607) ----------------
// 1024 rows x 512 pad cols x 2B = 1 MB. 512 blocks x 256 threads x 4 bf16.
__global__ __launch_bounds__(256) void zero_pads_kernel(bf16* __restrict__ Vtp) {
    int idx = blockIdx.x * 256 + threadIdx.x;      // 0..131071, each handles 4 bf16
    int row = idx >> 7;                            // 128 chunks of 4 per row
    int c4  = idx & 127;                           // 0..127
    int col = (c4 < 64) ? (c4 * 4) : (4352 + (c4 - 64) * 4);
    *(uint2*)(Vtp + (size_t)row * VTPW + col) = (uint2){0u, 0u};
}

// ---------------- fp32 -> bf16 cast of x ----------------
__global__ __launch_bounds__(256) void cast_x_kernel(const float* __restrict__ x,
                                                     bf16* __restrict__ xb) {
    int idx = blockIdx.x * 256 + threadIdx.x;
    float4 v = ((const float4*)x)[idx];
    uint2 o; o.x = pk2(v.x, v.y); o.y = pk2(v.z, v.w);
    ((uint2*)xb)[idx] = o;
}

// ---------------- transpose+cast the 5 weight matrices ----------------
struct WPtrs { const float* s[5]; bf16* d[5]; };
__global__ __launch_bounds__(256) void tcast_kernel(WPtrs p) {
    __shared__ float T[64][65];
    const float* in = p.s[blockIdx.z];
    bf16* out = p.d[blockIdx.z];
    const int t = threadIdx.x;
    const int r0 = blockIdx.x * 64, c0 = blockIdx.y * 64;
    #pragma unroll
    for (int c = 0; c < 4; ++c) {
        int row = (t >> 4) + c * 16, col = (t & 15) * 4;
        float4 v = *(const float4*)(in + (size_t)(r0 + row) * 1024 + c0 + col);
        T[row][col] = v.x; T[row][col + 1] = v.y; T[row][col + 2] = v.z; T[row][col + 3] = v.w;
    }
    __syncthreads();
    #pragma unroll
    for (int c = 0; c < 4; ++c) {
        int orow = (t >> 4) + c * 16, ocol = (t & 15) * 4;
        uint2 o;
        o.x = pk2(T[ocol][orow], T[ocol + 1][orow]);
        o.y = pk2(T[ocol + 2][orow], T[ocol + 3][orow]);
        *(uint2*)(out + (size_t)(c0 + orow) * 1024 + r0 + ocol) = o;
    }
}

// ---------------- bf16 MFMA GEMM: C[M,N] = act(alpha*A@Bt^T + bias) ----------------
// A row-major [M,K] stride lda; Bt row-major [N,K] stride ldb; C stride ldc.
// pv!=0: Bt base += (m0>>7)*128 (banded PV: per-128-j-tile column offset into Vtp).
template <int BM, int BN>
__global__ __launch_bounds__(256) void gemm_bt(
    const bf16* __restrict__ A, int lda, const bf16* __restrict__ Bt, int ldb,
    bf16* __restrict__ C, int ldc, int K,
    float alpha, const float* __restrict__ bias, int relu, int pv)
{
    constexpr int WM = BM / 2, WN = BN / 2, AI = WM / 16, BJ = WN / 16;
    __shared__ bf16 As[BM * 64];
    __shared__ bf16 Bs[BN * 64];
    const int t = threadIdx.x, l = t & 63, w = t >> 6;
    const int wr = w >> 1, wc = w & 1;
    const int jl = l & 15, g = l >> 4;
    const int m0 = blockIdx.y * BM, n0 = blockIdx.x * BN;
    const bf16* Btb = pv ? (Bt + (size_t)(m0 >> 7) * 128) : Bt;

    f32x4 acc[AI][BJ];
    #pragma unroll
    for (int i = 0; i < AI; ++i)
        #pragma unroll
        for (int j = 0; j < BJ; ++j) acc[i][j] = (f32x4){0.f, 0.f, 0.f, 0.f};

    for (int kk = 0; kk < K; kk += 64) {
        __syncthreads();
        #pragma unroll
        for (int c = 0; c < BM / 32; ++c) {
            int q = t + c * 256;
            int row = q >> 3;
            int kel = ((q & 7) ^ (row & 7)) << 3;
            gload_lds16(A + (size_t)(m0 + row) * lda + kk + kel,
                        (char*)As + (c * 256 + w * 64) * 16);
        }
        #pragma unroll
        for (int c = 0; c < BN / 32; ++c) {
            int q = t + c * 256;
            int row = q >> 3;
            int kel = ((q & 7) ^ (row & 7)) << 3;
            gload_lds16(Btb + (size_t)(n0 + row) * ldb + kk + kel,
                        (char*)Bs + (c * 256 + w * 64) * 16);
        }
        __syncthreads();
        #pragma unroll
        for (int ks = 0; ks < 2; ++ks) {
            bf16x8 af[AI], bfr[BJ];
            #pragma unroll
            for (int i = 0; i < AI; ++i) {
                int ra = wr * WM + i * 16 + jl;
                af[i] = *(const bf16x8*)((char*)As + ra * 128 + ((ks * 64 + g * 16) ^ ((ra & 7) << 4)));
            }
            #pragma unroll
            for (int j = 0; j < BJ; ++j) {
                int rb = wc * WN + j * 16 + jl;
                bfr[j] = *(const bf16x8*)((char*)Bs + rb * 128 + ((ks * 64 + g * 16) ^ ((rb & 7) << 4)));
            }
            #pragma unroll
            for (int i = 0; i < AI; ++i)
                #pragma unroll
                for (int j = 0; j < BJ; ++j)
                    acc[i][j] = __builtin_amdgcn_mfma_f32_16x16x32_bf16(af[i], bfr[j], acc[i][j], 0, 0, 0);
        }
    }

    const int g4 = g * 4;
    #pragma unroll
    for (int j = 0; j < BJ; ++j) {
        int col = n0 + wc * WN + j * 16 + jl;
        float bv = bias ? bias[col] : 0.f;
        #pragma unroll
        for (int i = 0; i < AI; ++i) {
            int rowb = m0 + wr * WM + i * 16 + g4;
            #pragma unroll
            for (int r = 0; r < 4; ++r) {
                float vv = alpha * acc[i][j][r] + bv;
                if (relu) vv = fmaxf(vv, 0.f);
                C[(size_t)(rowb + r) * ldc + col] = __float2bfloat16(vv);
            }
        }
    }
}

// ---------------- banded score GEMM: St[j][iw] = 0.06 * Q[win0+iw] . K[j] ----------------
// Block: (iw-chunk of 64) x (j-tile of 128). Q rows clamped (masked later by position).
__global__ __launch_bounds__(256) void score_gemm(const bf16* __restrict__ KQ,
                                                  bf16* __restrict__ St)
{
    constexpr int WM = 32, WN = 64, AI = 2, BJ = 4;
    __shared__ bf16 As[64 * 64];
    __shared__ bf16 Bs[128 * 64];
    const int t = threadIdx.x, l = t & 63, w = t >> 6;
    const int wr = w >> 1, wc = w & 1;
    const int jl = l & 15, g = l >> 4;
    const int tt = blockIdx.y;              // j-tile 0..31
    const int c0 = blockIdx.x * 64;         // iw chunk base
    const int win0 = tt * 128 - APP;        // window start
    const bf16* Qb = KQ + 1024;
    const bf16* Kb = KQ + (size_t)tt * 128 * KQS;

    f32x4 acc[AI][BJ];
    #pragma unroll
    for (int i = 0; i < AI; ++i)
        #pragma unroll
        for (int j = 0; j < BJ; ++j) acc[i][j] = (f32x4){0.f, 0.f, 0.f, 0.f};

    for (int kk = 0; kk < DIM; kk += 64) {
        __syncthreads();
        #pragma unroll
        for (int c = 0; c < 2; ++c) {
            int q = t + c * 256;
            int row = q >> 3;
            int kel = ((q & 7) ^ (row & 7)) << 3;
            int rg = win0 + c0 + row;
            rg = min(max(rg, 0), NROW - 1);
            gload_lds16(Qb + (size_t)rg * KQS + kk + kel,
                        (char*)As + (c * 256 + w * 64) * 16);
        }
        #pragma unroll
        for (int c = 0; c < 4; ++c) {
            int q = t + c * 256;
            int row = q >> 3;
            int kel = ((q & 7) ^ (row & 7)) << 3;
            gload_lds16(Kb + (size_t)row * KQS + kk + kel,
                        (char*)Bs + (c * 256 + w * 64) * 16);
        }
        __syncthreads();
        #pragma unroll
        for (int ks = 0; ks < 2; ++ks) {
            bf16x8 af[AI], bfr[BJ];
            #pragma unroll
            for (int i = 0; i < AI; ++i) {
                int ra = wr * WM + i * 16 + jl;
                af[i] = *(const bf16x8*)((char*)As + ra * 128 + ((ks * 64 + g * 16) ^ ((ra & 7) << 4)));
            }
            #pragma unroll
            for (int j = 0; j < BJ; ++j) {
                int rb = wc * WN + j * 16 + jl;
                bfr[j] = *(const bf16x8*)((char*)Bs + rb * 128 + ((ks * 64 + g * 16) ^ ((rb & 7) << 4)));
            }
            #pragma unroll
            for (int i = 0; i < AI; ++i)
                #pragma unroll
                for (int j = 0; j < BJ; ++j)
                    acc[i][j] = __builtin_amdgcn_mfma_f32_16x16x32_bf16(af[i], bfr[j], acc[i][j], 0, 0, 0);
        }
    }

    // epilogue: St[(tt*128 + j_local)*WIN + c0 + iw_local] = 0.06*acc  (r contiguous in iw)
    const int g4 = g * 4;
    #pragma unroll
    for (int j = 0; j < BJ; ++j) {
        int coll = wc * WN + j * 16 + jl;
        bf16* strow = St + (size_t)(tt * 128 + coll) * WIN;
        #pragma unroll
        for (int i = 0; i < AI; ++i) {
            int iwb = c0 + wr * WM + i * 16 + g4;
            #pragma unroll
            for (int r = 0; r < 4; ++r)
                strow[iwb + r] = __float2bfloat16(0.06f * acc[i][j][r]);
        }
    }
}

// ---------------- masked row softmax over the 640-wide band window ----------------
// Row j (tile tt=j>>7, jt=j&127): valid iw in [max(jt,256-128tt), min(jt+512,4351-128tt)].
__global__ __launch_bounds__(256) void softmax_band(bf16* __restrict__ St)
{
    const int w = threadIdx.x >> 6, l = threadIdx.x & 63;
    const int j = blockIdx.x * 4 + w;
    const int tt = j >> 7, jt = j & 127;
    unsigned* row = (unsigned*)(St + (size_t)j * WIN);
    const int lo = max(jt, 256 - 128 * tt);
    const int hi = min(jt + 512, 4351 - 128 * tt);
    unsigned u[5]; float v[10];
    #pragma unroll
    for (int c = 0; c < 5; ++c) u[c] = row[l + 64 * c];
    float m = -3e38f;
    #pragma unroll
    for (int c = 0; c < 5; ++c) {
        int iw = 2 * (l + 64 * c);
        v[2 * c]     = (iw >= lo && iw <= hi)         ? bu2f((unsigned short)(u[c] & 0xffff)) : -3e38f;
        v[2 * c + 1] = (iw + 1 >= lo && iw + 1 <= hi) ? bu2f((unsigned short)(u[c] >> 16))    : -3e38f;
        m = fmaxf(m, fmaxf(v[2 * c], v[2 * c + 1]));
    }
    #pragma unroll
    for (int off = 32; off > 0; off >>= 1) m = fmaxf(m, __shfl_xor(m, off));
    float s = 0.f;
    #pragma unroll
    for (int c = 0; c < 10; ++c) {
        float e = (v[c] > -1e37f) ? __expf(v[c] - m) : 0.f;
        v[c] = e; s += e;
    }
    #pragma unroll
    for (int off = 32; off > 0; off >>= 1) s += __shfl_xor(s, off);
    const float inv = 1.f / s;
    #pragma unroll
    for (int c = 0; c < 5; ++c)
        row[l + 64 * c] = pk2(v[2 * c] * inv, v[2 * c + 1] * inv);
}

// ---------------- LayerNorm: O = LN(T (+X)) * g + b ----------------
__global__ __launch_bounds__(256) void ln_kernel(
    const bf16* __restrict__ T, const float* __restrict__ X,
    const float* __restrict__ g, const float* __restrict__ b, bf16* __restrict__ O)
{
    __shared__ float red1[4], red2[4];
    const int r = blockIdx.x, t = threadIdx.x, lane = t & 63, w = t >> 6;
    ushort4 tv = ((const ushort4*)(T + (size_t)r * DIM))[t];
    float v0 = bu2f(tv.x), v1 = bu2f(tv.y), v2 = bu2f(tv.z), v3 = bu2f(tv.w);
    if (X) {
        float4 xv = ((const float4*)(X + (size_t)r * DIM))[t];
        v0 += xv.x; v1 += xv.y; v2 += xv.z; v3 += xv.w;
    }
    float s = v0 + v1 + v2 + v3;
    #pragma unroll
    for (int off = 32; off > 0; off >>= 1) s += __shfl_xor(s, off);
    if (lane == 0) red1[w] = s;
    __syncthreads();
    float mu = (red1[0] + red1[1] + red1[2] + red1[3]) * (1.f / DIM);
    float d0 = v0 - mu, d1 = v1 - mu, d2 = v2 - mu, d3 = v3 - mu;
    float s2 = d0 * d0 + d1 * d1 + d2 * d2 + d3 * d3;
    #pragma unroll
    for (int off = 32; off > 0; off >>= 1) s2 += __shfl_xor(s2, off);
    if (lane == 0) red2[w] = s2;
    __syncthreads();
    float var = (red2[0] + red2[1] + red2[2] + red2[3]) * (1.f / DIM);
    float rstd = rsqrtf(var + 1e-3f);
    float4 gv = ((const float4*)g)[t];
    float4 bv = ((const float4*)b)[t];
    uint2 o;
    o.x = pk2(d0 * rstd * gv.x + bv.x, d1 * rstd * gv.y + bv.y);
    o.y = pk2(d2 * rstd * gv.z + bv.z, d3 * rstd * gv.w + bv.w);
    ((uint2*)(O + (size_t)r * DIM))[t] = o;
}

// ---------------- out[r] = sigmoid(Y[r].wkd + bkd) ----------------
__global__ __launch_bounds__(256) void final_kernel(
    const bf16* __restrict__ Y, const float* __restrict__ wkd,
    const float* __restrict__ bkd, float* __restrict__ out)
{
    const int lane = threadIdx.x & 63, w = threadIdx.x >> 6;
    const int r = blockIdx.x * 4 + w;
    const bf16* yr = Y + (size_t)r * DIM;
    float s = 0.f;
    #pragma unroll
    for (int c = 0; c < 4; ++c) {
        ushort4 yv = ((const ushort4*)yr)[lane * 4 + c];
        float4 wv = ((const float4*)wkd)[lane * 4 + c];
        s += bu2f(yv.x) * wv.x + bu2f(yv.y) * wv.y + bu2f(yv.z) * wv.z + bu2f(yv.w) * wv.w;
    }
    #pragma unroll
    for (int off = 32; off > 0; off >>= 1) s += __shfl_xor(s, off);
    if (lane == 0) out[r] = 1.f / (1.f + __expf(-(s + bkd[0])));
}

extern "C" void kernel_launch(void* const* d_in, const int* in_sizes, int n_in,
                              void* d_out, int out_size, void* d_ws, size_t ws_size,
                              hipStream_t stream) {
    const float* x    = (const float*)d_in[0];
    const float* wk   = (const float*)d_in[1];
    const float* wq   = (const float*)d_in[2];
    const float* wv   = (const float*)d_in[3];
    const float* wo   = (const float*)d_in[4];
    const float* wka  = (const float*)d_in[5];
    const float* bka  = (const float*)d_in[6];
    const float* wkd  = (const float*)d_in[7];
    const float* bkd  = (const float*)d_in[8];
    const float* g_y  = (const float*)d_in[9];
    const float* b_y  = (const float*)d_in[10];
    const float* g_ka = (const float*)d_in[11];
    const float* b_ka = (const float*)d_in[12];
    float* out = (float*)d_out;

    char* ws = (char*)d_ws;
    const size_t MB = 1u << 20;
    const size_t NM = (size_t)NROW * DIM;
    // layout (peak 52 MB):
    bf16* woT  = (bf16*)(ws);              // 2 MB
    bf16* wkaT = (bf16*)(ws + 2 * MB);     // 2 MB
    bf16* fKQ  = (bf16*)(ws + 4 * MB);     // 16 MB [4096][2048]
    bf16* Vtp  = (bf16*)(ws + 20 * MB);    // 9 MB  [1024][4608] pad strips zeroed
    bf16* St   = (bf16*)(ws + 30 * MB);    // 5 MB  [4096][640]
    bf16* fY   = (bf16*)(ws + 36 * MB);    // 8 MB  [4096][1024] (PV out)
    bf16* wkT  = (bf16*)(ws + 36 * MB);    // overlay: dead before PV writes fY
    bf16* wqT  = (bf16*)(ws + 38 * MB);    //   (wkT|wqT contiguous 2048 rows)
    bf16* wvT  = (bf16*)(ws + 40 * MB);    // overlay
    bf16* xb   = (bf16*)(ws + 44 * MB);    // 8 MB
    bf16* fT   = fKQ;                      // wo out   (KQ dead after score)
    bf16* fL1  = fKQ + NM;                 // ln1 out
    bf16* fRel = Vtp;                      // wka out  (Vtp dead after PV)
    bf16* fT2  = fY;                       // ln2 out  (fY dead after wo)

    zero_pads_kernel<<<512, 256, 0, stream>>>(Vtp);
    cast_x_kernel<<<NROW * DIM / 4 / 256, 256, 0, stream>>>(x, xb);
    WPtrs wp;
    wp.s[0] = wk;  wp.s[1] = wq;  wp.s[2] = wv;  wp.s[3] = wo;  wp.s[4] = wka;
    wp.d[0] = wkT; wp.d[1] = wqT; wp.d[2] = wvT; wp.d[3] = woT; wp.d[4] = wkaT;
    tcast_kernel<<<dim3(16, 16, 5), 256, 0, stream>>>(wp);

    // KQ = xb @ [wkT;wqT]^T : [4096][2048]
    gemm_bt<128, 128><<<dim3(16, 32), 256, 0, stream>>>(
        xb, DIM, wkT, DIM, fKQ, KQS, DIM, 1.f, nullptr, 0, 0);
    // Vt (padded) = wvT @ xb^T : [1024][4096] into Vtp[:, 256:4352]
    gemm_bt<64, 128><<<dim3(32, 16), 256, 0, stream>>>(
        wvT, DIM, xb, DIM, Vtp + 2 * APP / 2 * 1, VTPW, DIM, 1.f, nullptr, 0, 0);

    score_gemm<<<dim3(WIN / 64, NROW / 128), 256, 0, stream>>>(fKQ, St);
    softmax_band<<<NROW / 4, 256, 0, stream>>>(St);
    // Y = St @ V(band) : gemm over K=640 with per-j-tile Vtp column offset
    gemm_bt<64, 128><<<dim3(8, 64), 256, 0, stream>>>(
        St, WIN, Vtp, VTPW, fY, DIM, WIN, 1.f, nullptr, 0, 1);

    gemm_bt<128, 64><<<dim3(16, 32), 256, 0, stream>>>(
        fY, DIM, woT, DIM, fT, DIM, DIM, 1.f, nullptr, 0, 0);
    ln_kernel<<<NROW, 256, 0, stream>>>(fT, x, g_y, b_y, fL1);
    gemm_bt<128, 64><<<dim3(16, 32), 256, 0, stream>>>(
        fL1, DIM, wkaT, DIM, fRel, DIM, DIM, 1.f, bka, 1, 0);
    ln_kernel<<<NROW, 256, 0, stream>>>(fRel, nullptr, g_ka, b_ka, fT2);
    final_kernel<<<NROW / 4, 256, 0, stream>>>(fT2, wkd, bkd, out);
}

// Round 7
// 141.699 us; speedup vs baseline: 1.4553x; 1.0383x over previous
//
#include <hip/hip_runtime.h>
#include <hip/hip_bf16.h>
#include <math.h>

typedef __hip_bfloat16 bf16;
typedef __attribute__((ext_vector_type(8))) short bf16x8;   // MFMA A/B frag (8 bf16)
typedef __attribute__((ext_vector_type(4))) float f32x4;    // MFMA C/D frag

#define NROW 4096
#define DIM  1024
#define APP  256
#define KQS  2048
#define WIN  640          // band window per 128-row j-tile: 128 + 2*APP
#define VTPW 4608         // padded Vt width: 256 | 4096 | 256

__device__ __forceinline__ unsigned short f2bu(float f) {
    bf16 h = __float2bfloat16(f);
    return *reinterpret_cast<unsigned short*>(&h);
}
__device__ __forceinline__ float bu2f(unsigned short u) {
    bf16 h; *reinterpret_cast<unsigned short*>(&h) = u;
    return __bfloat162float(h);
}
__device__ __forceinline__ unsigned pk2(float a, float b) {
    return (unsigned)f2bu(a) | ((unsigned)f2bu(b) << 16);
}
__device__ __forceinline__ void gload_lds16(const void* g, void* l) {
    __builtin_amdgcn_global_load_lds(
        (const __attribute__((address_space(1))) unsigned int*)g,
        (__attribute__((address_space(3))) unsigned int*)l, 16, 0, 0);
}

// ---------------- zero only the pad strips of Vtp (cols 0..255 and 4352..4607) ----------------
__global__ __launch_bounds__(256) void zero_pads_kernel(bf16* __restrict__ Vtp) {
    int idx = blockIdx.x * 256 + threadIdx.x;      // 0..131071, each handles 4 bf16
    int row = idx >> 7;
    int c4  = idx & 127;
    int col = (c4 < 64) ? (c4 * 4) : (4352 + (c4 - 64) * 4);
    *(uint2*)(Vtp + (size_t)row * VTPW + col) = (uint2){0u, 0u};
}

// ---------------- fp32 -> bf16 cast of x ----------------
__global__ __launch_bounds__(256) void cast_x_kernel(const float* __restrict__ x,
                                                     bf16* __restrict__ xb) {
    int idx = blockIdx.x * 256 + threadIdx.x;
    float4 v = ((const float4*)x)[idx];
    uint2 o; o.x = pk2(v.x, v.y); o.y = pk2(v.z, v.w);
    ((uint2*)xb)[idx] = o;
}

// ---------------- transpose+cast 4 weight matrices; z==4 = plain cast of wv ----------------
struct WPtrs { const float* s[5]; bf16* d[5]; };
__global__ __launch_bounds__(256) void tcast_kernel(WPtrs p) {
    __shared__ float T[64][65];
    const float* in = p.s[blockIdx.z];
    bf16* out = p.d[blockIdx.z];
    const int t = threadIdx.x;
    const int r0 = blockIdx.x * 64, c0 = blockIdx.y * 64;
    if (blockIdx.z == 4) {
        // plain cast, no transpose
        #pragma unroll
        for (int c = 0; c < 4; ++c) {
            int row = (t >> 4) + c * 16, col = (t & 15) * 4;
            float4 v = *(const float4*)(in + (size_t)(r0 + row) * 1024 + c0 + col);
            uint2 o; o.x = pk2(v.x, v.y); o.y = pk2(v.z, v.w);
            *(uint2*)(out + (size_t)(r0 + row) * 1024 + c0 + col) = o;
        }
        return;
    }
    #pragma unroll
    for (int c = 0; c < 4; ++c) {
        int row = (t >> 4) + c * 16, col = (t & 15) * 4;
        float4 v = *(const float4*)(in + (size_t)(r0 + row) * 1024 + c0 + col);
        T[row][col] = v.x; T[row][col + 1] = v.y; T[row][col + 2] = v.z; T[row][col + 3] = v.w;
    }
    __syncthreads();
    #pragma unroll
    for (int c = 0; c < 4; ++c) {
        int orow = (t >> 4) + c * 16, ocol = (t & 15) * 4;
        uint2 o;
        o.x = pk2(T[ocol][orow], T[ocol + 1][orow]);
        o.y = pk2(T[ocol + 2][orow], T[ocol + 3][orow]);
        *(uint2*)(out + (size_t)(c0 + orow) * 1024 + r0 + ocol) = o;
    }
}

// ---------------- bf16 MFMA GEMM: C[M,N] = act(alpha*A@Bt^T + bias) ----------------
// A row-major [M,K] stride lda; Bt row-major [N,K] stride ldb; C stride ldc.
// pv!=0: Bt base += (m0>>7)*128 (banded PV: per-128-j-tile column offset into Vtp).
template <int BM, int BN>
__global__ __launch_bounds__(256) void gemm_bt(
    const bf16* __restrict__ A, int lda, const bf16* __restrict__ Bt, int ldb,
    bf16* __restrict__ C, int ldc, int K,
    float alpha, const float* __restrict__ bias, int relu, int pv)
{
    constexpr int WM = BM / 2, WN = BN / 2, AI = WM / 16, BJ = WN / 16;
    __shared__ bf16 As[BM * 64];
    __shared__ bf16 Bs[BN * 64];
    const int t = threadIdx.x, l = t & 63, w = t >> 6;
    const int wr = w >> 1, wc = w & 1;
    const int jl = l & 15, g = l >> 4;
    const int m0 = blockIdx.y * BM, n0 = blockIdx.x * BN;
    const bf16* Btb = pv ? (Bt + (size_t)(m0 >> 7) * 128) : Bt;

    f32x4 acc[AI][BJ];
    #pragma unroll
    for (int i = 0; i < AI; ++i)
        #pragma unroll
        for (int j = 0; j < BJ; ++j) acc[i][j] = (f32x4){0.f, 0.f, 0.f, 0.f};

    for (int kk = 0; kk < K; kk += 64) {
        __syncthreads();
        #pragma unroll
        for (int c = 0; c < BM / 32; ++c) {
            int q = t + c * 256;
            int row = q >> 3;
            int kel = ((q & 7) ^ (row & 7)) << 3;
            gload_lds16(A + (size_t)(m0 + row) * lda + kk + kel,
                        (char*)As + (c * 256 + w * 64) * 16);
        }
        #pragma unroll
        for (int c = 0; c < BN / 32; ++c) {
            int q = t + c * 256;
            int row = q >> 3;
            int kel = ((q & 7) ^ (row & 7)) << 3;
            gload_lds16(Btb + (size_t)(n0 + row) * ldb + kk + kel,
                        (char*)Bs + (c * 256 + w * 64) * 16);
        }
        __syncthreads();
        #pragma unroll
        for (int ks = 0; ks < 2; ++ks) {
            bf16x8 af[AI], bfr[BJ];
            #pragma unroll
            for (int i = 0; i < AI; ++i) {
                int ra = wr * WM + i * 16 + jl;
                af[i] = *(const bf16x8*)((char*)As + ra * 128 + ((ks * 64 + g * 16) ^ ((ra & 7) << 4)));
            }
            #pragma unroll
            for (int j = 0; j < BJ; ++j) {
                int rb = wc * WN + j * 16 + jl;
                bfr[j] = *(const bf16x8*)((char*)Bs + rb * 128 + ((ks * 64 + g * 16) ^ ((rb & 7) << 4)));
            }
            #pragma unroll
            for (int i = 0; i < AI; ++i)
                #pragma unroll
                for (int j = 0; j < BJ; ++j)
                    acc[i][j] = __builtin_amdgcn_mfma_f32_16x16x32_bf16(af[i], bfr[j], acc[i][j], 0, 0, 0);
        }
    }

    const int g4 = g * 4;
    #pragma unroll
    for (int j = 0; j < BJ; ++j) {
        int col = n0 + wc * WN + j * 16 + jl;
        float bv = bias ? bias[col] : 0.f;
        #pragma unroll
        for (int i = 0; i < AI; ++i) {
            int rowb = m0 + wr * WM + i * 16 + g4;
            #pragma unroll
            for (int r = 0; r < 4; ++r) {
                float vv = alpha * acc[i][j][r] + bv;
                if (relu) vv = fmaxf(vv, 0.f);
                C[(size_t)(rowb + r) * ldc + col] = __float2bfloat16(vv);
            }
        }
    }
}

// ---------------- banded score GEMM: St[j][iw] = 0.06 * Q[win0+iw] . K[j] ----------------
__global__ __launch_bounds__(256) void score_gemm(const bf16* __restrict__ KQ,
                                                  bf16* __restrict__ St)
{
    constexpr int WM = 32, WN = 64, AI = 2, BJ = 4;
    __shared__ bf16 As[64 * 64];
    __shared__ bf16 Bs[128 * 64];
    const int t = threadIdx.x, l = t & 63, w = t >> 6;
    const int wr = w >> 1, wc = w & 1;
    const int jl = l & 15, g = l >> 4;
    const int tt = blockIdx.y;              // j-tile 0..31
    const int c0 = blockIdx.x * 64;         // iw chunk base
    const int win0 = tt * 128 - APP;        // window start
    const bf16* Qb = KQ + 1024;
    const bf16* Kb = KQ + (size_t)tt * 128 * KQS;

    f32x4 acc[AI][BJ];
    #pragma unroll
    for (int i = 0; i < AI; ++i)
        #pragma unroll
        for (int j = 0; j < BJ; ++j) acc[i][j] = (f32x4){0.f, 0.f, 0.f, 0.f};

    for (int kk = 0; kk < DIM; kk += 64) {
        __syncthreads();
        #pragma unroll
        for (int c = 0; c < 2; ++c) {
            int q = t + c * 256;
            int row = q >> 3;
            int kel = ((q & 7) ^ (row & 7)) << 3;
            int rg = win0 + c0 + row;
            rg = min(max(rg, 0), NROW - 1);
            gload_lds16(Qb + (size_t)rg * KQS + kk + kel,
                        (char*)As + (c * 256 + w * 64) * 16);
        }
        #pragma unroll
        for (int c = 0; c < 4; ++c) {
            int q = t + c * 256;
            int row = q >> 3;
            int kel = ((q & 7) ^ (row & 7)) << 3;
            gload_lds16(Kb + (size_t)row * KQS + kk + kel,
                        (char*)Bs + (c * 256 + w * 64) * 16);
        }
        __syncthreads();
        #pragma unroll
        for (int ks = 0; ks < 2; ++ks) {
            bf16x8 af[AI], bfr[BJ];
            #pragma unroll
            for (int i = 0; i < AI; ++i) {
                int ra = wr * WM + i * 16 + jl;
                af[i] = *(const bf16x8*)((char*)As + ra * 128 + ((ks * 64 + g * 16) ^ ((ra & 7) << 4)));
            }
            #pragma unroll
            for (int j = 0; j < BJ; ++j) {
                int rb = wc * WN + j * 16 + jl;
                bfr[j] = *(const bf16x8*)((char*)Bs + rb * 128 + ((ks * 64 + g * 16) ^ ((rb & 7) << 4)));
            }
            #pragma unroll
            for (int i = 0; i < AI; ++i)
                #pragma unroll
                for (int j = 0; j < BJ; ++j)
                    acc[i][j] = __builtin_amdgcn_mfma_f32_16x16x32_bf16(af[i], bfr[j], acc[i][j], 0, 0, 0);
        }
    }

    const int g4 = g * 4;
    #pragma unroll
    for (int j = 0; j < BJ; ++j) {
        int coll = wc * WN + j * 16 + jl;
        bf16* strow = St + (size_t)(tt * 128 + coll) * WIN;
        #pragma unroll
        for (int i = 0; i < AI; ++i) {
            int iwb = c0 + wr * WM + i * 16 + g4;
            #pragma unroll
            for (int r = 0; r < 4; ++r)
                strow[iwb + r] = __float2bfloat16(0.06f * acc[i][j][r]);
        }
    }
}

// ---------------- masked row softmax over the 640-wide band window ----------------
__global__ __launch_bounds__(256) void softmax_band(bf16* __restrict__ St)
{
    const int w = threadIdx.x >> 6, l = threadIdx.x & 63;
    const int j = blockIdx.x * 4 + w;
    const int tt = j >> 7, jt = j & 127;
    unsigned* row = (unsigned*)(St + (size_t)j * WIN);
    const int lo = max(jt, 256 - 128 * tt);
    const int hi = min(jt + 512, 4351 - 128 * tt);
    unsigned u[5]; float v[10];
    #pragma unroll
    for (int c = 0; c < 5; ++c) u[c] = row[l + 64 * c];
    float m = -3e38f;
    #pragma unroll
    for (int c = 0; c < 5; ++c) {
        int iw = 2 * (l + 64 * c);
        v[2 * c]     = (iw >= lo && iw <= hi)         ? bu2f((unsigned short)(u[c] & 0xffff)) : -3e38f;
        v[2 * c + 1] = (iw + 1 >= lo && iw + 1 <= hi) ? bu2f((unsigned short)(u[c] >> 16))    : -3e38f;
        m = fmaxf(m, fmaxf(v[2 * c], v[2 * c + 1]));
    }
    #pragma unroll
    for (int off = 32; off > 0; off >>= 1) m = fmaxf(m, __shfl_xor(m, off));
    float s = 0.f;
    #pragma unroll
    for (int c = 0; c < 10; ++c) {
        float e = (v[c] > -1e37f) ? __expf(v[c] - m) : 0.f;
        v[c] = e; s += e;
    }
    #pragma unroll
    for (int off = 32; off > 0; off >>= 1) s += __shfl_xor(s, off);
    const float inv = 1.f / s;
    #pragma unroll
    for (int c = 0; c < 5; ++c)
        row[l + 64 * c] = pk2(v[2 * c] * inv, v[2 * c + 1] * inv);
}

// ---------------- LayerNorm: O = LN(T (+X)) * g + b ----------------
__global__ __launch_bounds__(256) void ln_kernel(
    const bf16* __restrict__ T, const float* __restrict__ X,
    const float* __restrict__ g, const float* __restrict__ b, bf16* __restrict__ O)
{
    __shared__ float red1[4], red2[4];
    const int r = blockIdx.x, t = threadIdx.x, lane = t & 63, w = t >> 6;
    ushort4 tv = ((const ushort4*)(T + (size_t)r * DIM))[t];
    float v0 = bu2f(tv.x), v1 = bu2f(tv.y), v2 = bu2f(tv.z), v3 = bu2f(tv.w);
    if (X) {
        float4 xv = ((const float4*)(X + (size_t)r * DIM))[t];
        v0 += xv.x; v1 += xv.y; v2 += xv.z; v3 += xv.w;
    }
    float s = v0 + v1 + v2 + v3;
    #pragma unroll
    for (int off = 32; off > 0; off >>= 1) s += __shfl_xor(s, off);
    if (lane == 0) red1[w] = s;
    __syncthreads();
    float mu = (red1[0] + red1[1] + red1[2] + red1[3]) * (1.f / DIM);
    float d0 = v0 - mu, d1 = v1 - mu, d2 = v2 - mu, d3 = v3 - mu;
    float s2 = d0 * d0 + d1 * d1 + d2 * d2 + d3 * d3;
    #pragma unroll
    for (int off = 32; off > 0; off >>= 1) s2 += __shfl_xor(s2, off);
    if (lane == 0) red2[w] = s2;
    __syncthreads();
    float var = (red2[0] + red2[1] + red2[2] + red2[3]) * (1.f / DIM);
    float rstd = rsqrtf(var + 1e-3f);
    float4 gv = ((const float4*)g)[t];
    float4 bv = ((const float4*)b)[t];
    uint2 o;
    o.x = pk2(d0 * rstd * gv.x + bv.x, d1 * rstd * gv.y + bv.y);
    o.y = pk2(d2 * rstd * gv.z + bv.z, d3 * rstd * gv.w + bv.w);
    ((uint2*)(O + (size_t)r * DIM))[t] = o;
}

// ---------------- out[r] = sigmoid(Y[r].wkd + bkd) ----------------
__global__ __launch_bounds__(256) void final_kernel(
    const bf16* __restrict__ Y, const float* __restrict__ wkd,
    const float* __restrict__ bkd, float* __restrict__ out)
{
    const int lane = threadIdx.x & 63, w = threadIdx.x >> 6;
    const int r = blockIdx.x * 4 + w;
    const bf16* yr = Y + (size_t)r * DIM;
    float s = 0.f;
    #pragma unroll
    for (int c = 0; c < 4; ++c) {
        ushort4 yv = ((const ushort4*)yr)[lane * 4 + c];
        float4 wv = ((const float4*)wkd)[lane * 4 + c];
        s += bu2f(yv.x) * wv.x + bu2f(yv.y) * wv.y + bu2f(yv.z) * wv.z + bu2f(yv.w) * wv.w;
    }
    #pragma unroll
    for (int off = 32; off > 0; off >>= 1) s += __shfl_xor(s, off);
    if (lane == 0) out[r] = 1.f / (1.f + __expf(-(s + bkd[0])));
}

extern "C" void kernel_launch(void* const* d_in, const int* in_sizes, int n_in,
                              void* d_out, int out_size, void* d_ws, size_t ws_size,
                              hipStream_t stream) {
    const float* x    = (const float*)d_in[0];
    const float* wk   = (const float*)d_in[1];
    const float* wq   = (const float*)d_in[2];
    const float* wv   = (const float*)d_in[3];
    const float* wo   = (const float*)d_in[4];
    const float* wka  = (const float*)d_in[5];
    const float* bka  = (const float*)d_in[6];
    const float* wkd  = (const float*)d_in[7];
    const float* bkd  = (const float*)d_in[8];
    const float* g_y  = (const float*)d_in[9];
    const float* b_y  = (const float*)d_in[10];
    const float* g_ka = (const float*)d_in[11];
    const float* b_ka = (const float*)d_in[12];
    float* out = (float*)d_out;

    char* ws = (char*)d_ws;
    const size_t MB = 1u << 20;
    const size_t NM = (size_t)NROW * DIM;
    // layout (peak 52 MB):
    bf16* woT  = (bf16*)(ws);              // 2 MB   wo^T
    bf16* wkaT = (bf16*)(ws + 2 * MB);     // 2 MB
    bf16* fKQ  = (bf16*)(ws + 4 * MB);     // 16 MB [4096][2048]
    bf16* Vtp  = (bf16*)(ws + 20 * MB);    // 9 MB  [1024][4608] = (x@wvo)^T padded
    bf16* St   = (bf16*)(ws + 30 * MB);    // 5 MB  [4096][640]
    bf16* fT   = (bf16*)(ws + 36 * MB);    // 8 MB  PV out = y@wo (pre-residual)
    bf16* wkT  = (bf16*)(ws + 36 * MB);    // overlay: dead after KQ gemm
    bf16* wqT  = (bf16*)(ws + 38 * MB);    //   (wkT|wqT contiguous 2048 rows)
    bf16* wvB  = (bf16*)(ws + 40 * MB);    // overlay: wv plain bf16 (dead after wvoT gemm)
    bf16* wvoT = (bf16*)(ws + 42 * MB);    // overlay: (wv@wo)^T (dead after Vt gemm)
    bf16* xb   = (bf16*)(ws + 44 * MB);    // 8 MB  (dead after Vt gemm)
    bf16* fL1  = fKQ + NM;                 // ln1 out (fKQ dead after score)
    bf16* fRel = Vtp;                      // wka out (Vtp dead after PV)
    bf16* fT2  = fT;                       // ln2 out (fT dead after ln1)

    zero_pads_kernel<<<512, 256, 0, stream>>>(Vtp);
    cast_x_kernel<<<NROW * DIM / 4 / 256, 256, 0, stream>>>(x, xb);
    WPtrs wp;
    wp.s[0] = wk;  wp.s[1] = wq;  wp.s[2] = wo;  wp.s[3] = wka;  wp.s[4] = wv;
    wp.d[0] = wkT; wp.d[1] = wqT; wp.d[2] = woT; wp.d[3] = wkaT; wp.d[4] = wvB;
    tcast_kernel<<<dim3(16, 16, 5), 256, 0, stream>>>(wp);

    // wvoT = (wv@wo)^T = wo^T @ wv^T : A=woT (row-major wo^T), Bt=wvB (row-major wv)
    gemm_bt<64, 64><<<dim3(16, 16), 256, 0, stream>>>(
        woT, DIM, wvB, DIM, wvoT, DIM, DIM, 1.f, nullptr, 0, 0);
    // KQ = xb @ [wkT;wqT]^T : [4096][2048]
    gemm_bt<128, 128><<<dim3(16, 32), 256, 0, stream>>>(
        xb, DIM, wkT, DIM, fKQ, KQS, DIM, 1.f, nullptr, 0, 0);
    // V'^T (padded) = wvoT @ xb^T : [1024][4096] into Vtp[:, 256:4352]
    gemm_bt<64, 128><<<dim3(32, 16), 256, 0, stream>>>(
        wvoT, DIM, xb, DIM, Vtp + 256, VTPW, DIM, 1.f, nullptr, 0, 0);

    score_gemm<<<dim3(WIN / 64, NROW / 128), 256, 0, stream>>>(fKQ, St);
    softmax_band<<<NROW / 4, 256, 0, stream>>>(St);
    // t = y@wo = St @ V'(band) : K=640 with per-j-tile Vtp column offset
    gemm_bt<64, 128><<<dim3(8, 64), 256, 0, stream>>>(
        St, WIN, Vtp, VTPW, fT, DIM, WIN, 1.f, nullptr, 0, 1);

    ln_kernel<<<NROW, 256, 0, stream>>>(fT, x, g_y, b_y, fL1);
    gemm_bt<128, 64><<<dim3(16, 32), 256, 0, stream>>>(
        fL1, DIM, wkaT, DIM, fRel, DIM, DIM, 1.f, bka, 1, 0);
    ln_kernel<<<NROW, 256, 0, stream>>>(fRel, nullptr, g_ka, b_ka, fT2);
    final_kernel<<<NROW / 4, 256, 0, stream>>>(fT2, wkd, bkd, out);
}

// Round 8
// 130.475 us; speedup vs baseline: 1.5805x; 1.0860x over previous
//
#include <hip/hip_runtime.h>
#include <hip/hip_bf16.h>
#include <math.h>

typedef __hip_bfloat16 bf16;
typedef __attribute__((ext_vector_type(8))) short bf16x8;   // MFMA A/B frag (8 bf16)
typedef __attribute__((ext_vector_type(4))) float f32x4;    // MFMA C/D frag

#define NROW 4096
#define DIM  1024
#define APP  256
#define WIN  640          // band window per 128-row j-tile: 128 + 2*APP
#define VTPW 4608         // padded Vt width: 256 | 4096 | 256

__device__ __forceinline__ unsigned short f2bu(float f) {
    bf16 h = __float2bfloat16(f);
    return *reinterpret_cast<unsigned short*>(&h);
}
__device__ __forceinline__ float bu2f(unsigned short u) {
    bf16 h; *reinterpret_cast<unsigned short*>(&h) = u;
    return __bfloat162float(h);
}
__device__ __forceinline__ unsigned pk2(float a, float b) {
    return (unsigned)f2bu(a) | ((unsigned)f2bu(b) << 16);
}
__device__ __forceinline__ void gload_lds16(const void* g, void* l) {
    __builtin_amdgcn_global_load_lds(
        (const __attribute__((address_space(1))) unsigned int*)g,
        (__attribute__((address_space(3))) unsigned int*)l, 16, 0, 0);
}

// ---------------- zero only the pad strips of Vtp (cols 0..255 and 4352..4607) ----------------
__global__ __launch_bounds__(256) void zero_pads_kernel(bf16* __restrict__ Vtp) {
    int idx = blockIdx.x * 256 + threadIdx.x;
    int row = idx >> 7;
    int c4  = idx & 127;
    int col = (c4 < 64) ? (c4 * 4) : (4352 + (c4 - 64) * 4);
    *(uint2*)(Vtp + (size_t)row * VTPW + col) = (uint2){0u, 0u};
}

// ---------------- fp32 -> bf16 cast of x ----------------
__global__ __launch_bounds__(256) void cast_x_kernel(const float* __restrict__ x,
                                                     bf16* __restrict__ xb) {
    int idx = blockIdx.x * 256 + threadIdx.x;
    float4 v = ((const float4*)x)[idx];
    uint2 o; o.x = pk2(v.x, v.y); o.y = pk2(v.z, v.w);
    ((uint2*)xb)[idx] = o;
}

// ---------------- weight prep: z<3 plain cast (wk,wq,wv); z>=3 transpose+cast (wo,wka) ----------------
struct WPtrs { const float* s[5]; bf16* d[5]; };
__global__ __launch_bounds__(256) void tcast_kernel(WPtrs p) {
    __shared__ float T[64][65];
    const float* in = p.s[blockIdx.z];
    bf16* out = p.d[blockIdx.z];
    const int t = threadIdx.x;
    const int r0 = blockIdx.x * 64, c0 = blockIdx.y * 64;
    if (blockIdx.z < 3) {
        #pragma unroll
        for (int c = 0; c < 4; ++c) {
            int row = (t >> 4) + c * 16, col = (t & 15) * 4;
            float4 v = *(const float4*)(in + (size_t)(r0 + row) * 1024 + c0 + col);
            uint2 o; o.x = pk2(v.x, v.y); o.y = pk2(v.z, v.w);
            *(uint2*)(out + (size_t)(r0 + row) * 1024 + c0 + col) = o;
        }
        return;
    }
    #pragma unroll
    for (int c = 0; c < 4; ++c) {
        int row = (t >> 4) + c * 16, col = (t & 15) * 4;
        float4 v = *(const float4*)(in + (size_t)(r0 + row) * 1024 + c0 + col);
        T[row][col] = v.x; T[row][col + 1] = v.y; T[row][col + 2] = v.z; T[row][col + 3] = v.w;
    }
    __syncthreads();
    #pragma unroll
    for (int c = 0; c < 4; ++c) {
        int orow = (t >> 4) + c * 16, ocol = (t & 15) * 4;
        uint2 o;
        o.x = pk2(T[ocol][orow], T[ocol + 1][orow]);
        o.y = pk2(T[ocol + 2][orow], T[ocol + 3][orow]);
        *(uint2*)(out + (size_t)(c0 + orow) * 1024 + r0 + ocol) = o;
    }
}

// ---------------- bf16 MFMA GEMM: C[M,N] = act(alpha*A@Bt^T + bias) ----------------
// A row-major [M,K] stride lda; Bt row-major [N,K] stride ldb; C stride ldc.
// pv!=0: Bt base += (m0>>7)*128 (banded PV: per-128-j-tile column offset into Vtp).
template <int BM, int BN>
__global__ __launch_bounds__(256) void gemm_bt(
    const bf16* __restrict__ A, int lda, const bf16* __restrict__ Bt, int ldb,
    bf16* __restrict__ C, int ldc, int K,
    float alpha, const float* __restrict__ bias, int relu, int pv)
{
    constexpr int WM = BM / 2, WN = BN / 2, AI = WM / 16, BJ = WN / 16;
    __shared__ bf16 As[BM * 64];
    __shared__ bf16 Bs[BN * 64];
    const int t = threadIdx.x, l = t & 63, w = t >> 6;
    const int wr = w >> 1, wc = w & 1;
    const int jl = l & 15, g = l >> 4;
    const int m0 = blockIdx.y * BM, n0 = blockIdx.x * BN;
    const bf16* Btb = pv ? (Bt + (size_t)(m0 >> 7) * 128) : Bt;

    f32x4 acc[AI][BJ];
    #pragma unroll
    for (int i = 0; i < AI; ++i)
        #pragma unroll
        for (int j = 0; j < BJ; ++j) acc[i][j] = (f32x4){0.f, 0.f, 0.f, 0.f};

    for (int kk = 0; kk < K; kk += 64) {
        __syncthreads();
        #pragma unroll
        for (int c = 0; c < BM / 32; ++c) {
            int q = t + c * 256;
            int row = q >> 3;
            int kel = ((q & 7) ^ (row & 7)) << 3;
            gload_lds16(A + (size_t)(m0 + row) * lda + kk + kel,
                        (char*)As + (c * 256 + w * 64) * 16);
        }
        #pragma unroll
        for (int c = 0; c < BN / 32; ++c) {
            int q = t + c * 256;
            int row = q >> 3;
            int kel = ((q & 7) ^ (row & 7)) << 3;
            gload_lds16(Btb + (size_t)(n0 + row) * ldb + kk + kel,
                        (char*)Bs + (c * 256 + w * 64) * 16);
        }
        __syncthreads();
        #pragma unroll
        for (int ks = 0; ks < 2; ++ks) {
            bf16x8 af[AI], bfr[BJ];
            #pragma unroll
            for (int i = 0; i < AI; ++i) {
                int ra = wr * WM + i * 16 + jl;
                af[i] = *(const bf16x8*)((char*)As + ra * 128 + ((ks * 64 + g * 16) ^ ((ra & 7) << 4)));
            }
            #pragma unroll
            for (int j = 0; j < BJ; ++j) {
                int rb = wc * WN + j * 16 + jl;
                bfr[j] = *(const bf16x8*)((char*)Bs + rb * 128 + ((ks * 64 + g * 16) ^ ((rb & 7) << 4)));
            }
            #pragma unroll
            for (int i = 0; i < AI; ++i)
                #pragma unroll
                for (int j = 0; j < BJ; ++j)
                    acc[i][j] = __builtin_amdgcn_mfma_f32_16x16x32_bf16(af[i], bfr[j], acc[i][j], 0, 0, 0);
        }
    }

    const int g4 = g * 4;
    #pragma unroll
    for (int j = 0; j < BJ; ++j) {
        int col = n0 + wc * WN + j * 16 + jl;
        float bv = bias ? bias[col] : 0.f;
        #pragma unroll
        for (int i = 0; i < AI; ++i) {
            int rowb = m0 + wr * WM + i * 16 + g4;
            #pragma unroll
            for (int r = 0; r < 4; ++r) {
                float vv = alpha * acc[i][j][r] + bv;
                if (relu) vv = fmaxf(vv, 0.f);
                C[(size_t)(rowb + r) * ldc + col] = __float2bfloat16(vv);
            }
        }
    }
}

// ---------------- two 1024^3 mini GEMMs in one launch (z=0: WqkT=wk@wq^T, z=1: wvoT=wo^T@wv^T) ----------------
struct MiniPtrs { const bf16* A[2]; const bf16* Bt[2]; bf16* C[2]; };
__global__ __launch_bounds__(256) void gemm_mini(MiniPtrs p) {
    constexpr int BM = 64, BN = 64, WM = 32, WN = 32, AI = 2, BJ = 2;
    __shared__ bf16 As[BM * 64];
    __shared__ bf16 Bs[BN * 64];
    const bf16* A  = p.A[blockIdx.z];
    const bf16* Bt = p.Bt[blockIdx.z];
    bf16* C        = p.C[blockIdx.z];
    const int t = threadIdx.x, l = t & 63, w = t >> 6;
    const int wr = w >> 1, wc = w & 1;
    const int jl = l & 15, g = l >> 4;
    const int m0 = blockIdx.y * BM, n0 = blockIdx.x * BN;

    f32x4 acc[AI][BJ];
    #pragma unroll
    for (int i = 0; i < AI; ++i)
        #pragma unroll
        for (int j = 0; j < BJ; ++j) acc[i][j] = (f32x4){0.f, 0.f, 0.f, 0.f};

    for (int kk = 0; kk < DIM; kk += 64) {
        __syncthreads();
        #pragma unroll
        for (int c = 0; c < 2; ++c) {
            int q = t + c * 256;
            int row = q >> 3;
            int kel = ((q & 7) ^ (row & 7)) << 3;
            gload_lds16(A + (size_t)(m0 + row) * DIM + kk + kel,
                        (char*)As + (c * 256 + w * 64) * 16);
            gload_lds16(Bt + (size_t)(n0 + row) * DIM + kk + kel,
                        (char*)Bs + (c * 256 + w * 64) * 16);
        }
        __syncthreads();
        #pragma unroll
        for (int ks = 0; ks < 2; ++ks) {
            bf16x8 af[AI], bfr[BJ];
            #pragma unroll
            for (int i = 0; i < AI; ++i) {
                int ra = wr * WM + i * 16 + jl;
                af[i] = *(const bf16x8*)((char*)As + ra * 128 + ((ks * 64 + g * 16) ^ ((ra & 7) << 4)));
            }
            #pragma unroll
            for (int j = 0; j < BJ; ++j) {
                int rb = wc * WN + j * 16 + jl;
                bfr[j] = *(const bf16x8*)((char*)Bs + rb * 128 + ((ks * 64 + g * 16) ^ ((rb & 7) << 4)));
            }
            #pragma unroll
            for (int i = 0; i < AI; ++i)
                #pragma unroll
                for (int j = 0; j < BJ; ++j)
                    acc[i][j] = __builtin_amdgcn_mfma_f32_16x16x32_bf16(af[i], bfr[j], acc[i][j], 0, 0, 0);
        }
    }

    const int g4 = g * 4;
    #pragma unroll
    for (int j = 0; j < BJ; ++j) {
        int col = n0 + wc * WN + j * 16 + jl;
        #pragma unroll
        for (int i = 0; i < AI; ++i) {
            int rowb = m0 + wr * WM + i * 16 + g4;
            #pragma unroll
            for (int r = 0; r < 4; ++r)
                C[(size_t)(rowb + r) * DIM + col] = __float2bfloat16(acc[i][j][r]);
        }
    }
}

// ---------------- banded score GEMM: St[j][iw] = 0.06 * Qh[win0+iw] . x[j] ----------------
__global__ __launch_bounds__(256) void score_gemm(const bf16* __restrict__ Qh,
                                                  const bf16* __restrict__ xb,
                                                  bf16* __restrict__ St)
{
    constexpr int WM = 32, WN = 64, AI = 2, BJ = 4;
    __shared__ bf16 As[64 * 64];
    __shared__ bf16 Bs[128 * 64];
    const int t = threadIdx.x, l = t & 63, w = t >> 6;
    const int wr = w >> 1, wc = w & 1;
    const int jl = l & 15, g = l >> 4;
    const int tt = blockIdx.y;              // j-tile 0..31
    const int c0 = blockIdx.x * 64;         // iw chunk base
    const int win0 = tt * 128 - APP;        // window start
    const bf16* Kb = xb + (size_t)tt * 128 * DIM;

    f32x4 acc[AI][BJ];
    #pragma unroll
    for (int i = 0; i < AI; ++i)
        #pragma unroll
        for (int j = 0; j < BJ; ++j) acc[i][j] = (f32x4){0.f, 0.f, 0.f, 0.f};

    for (int kk = 0; kk < DIM; kk += 64) {
        __syncthreads();
        #pragma unroll
        for (int c = 0; c < 2; ++c) {
            int q = t + c * 256;
            int row = q >> 3;
            int kel = ((q & 7) ^ (row & 7)) << 3;
            int rg = win0 + c0 + row;
            rg = min(max(rg, 0), NROW - 1);
            gload_lds16(Qh + (size_t)rg * DIM + kk + kel,
                        (char*)As + (c * 256 + w * 64) * 16);
        }
        #pragma unroll
        for (int c = 0; c < 4; ++c) {
            int q = t + c * 256;
            int row = q >> 3;
            int kel = ((q & 7) ^ (row & 7)) << 3;
            gload_lds16(Kb + (size_t)row * DIM + kk + kel,
                        (char*)Bs + (c * 256 + w * 64) * 16);
        }
        __syncthreads();
        #pragma unroll
        for (int ks = 0; ks < 2; ++ks) {
            bf16x8 af[AI], bfr[BJ];
            #pragma unroll
            for (int i = 0; i < AI; ++i) {
                int ra = wr * WM + i * 16 + jl;
                af[i] = *(const bf16x8*)((char*)As + ra * 128 + ((ks * 64 + g * 16) ^ ((ra & 7) << 4)));
            }
            #pragma unroll
            for (int j = 0; j < BJ; ++j) {
                int rb = wc * WN + j * 16 + jl;
                bfr[j] = *(const bf16x8*)((char*)Bs + rb * 128 + ((ks * 64 + g * 16) ^ ((rb & 7) << 4)));
            }
            #pragma unroll
            for (int i = 0; i < AI; ++i)
                #pragma unroll
                for (int j = 0; j < BJ; ++j)
                    acc[i][j] = __builtin_amdgcn_mfma_f32_16x16x32_bf16(af[i], bfr[j], acc[i][j], 0, 0, 0);
        }
    }

    const int g4 = g * 4;
    #pragma unroll
    for (int j = 0; j < BJ; ++j) {
        int coll = wc * WN + j * 16 + jl;
        bf16* strow = St + (size_t)(tt * 128 + coll) * WIN;
        #pragma unroll
        for (int i = 0; i < AI; ++i) {
            int iwb = c0 + wr * WM + i * 16 + g4;
            #pragma unroll
            for (int r = 0; r < 4; ++r)
                strow[iwb + r] = __float2bfloat16(0.06f * acc[i][j][r]);
        }
    }
}

// ---------------- masked row softmax over the 640-wide band window ----------------
__global__ __launch_bounds__(256) void softmax_band(bf16* __restrict__ St)
{
    const int w = threadIdx.x >> 6, l = threadIdx.x & 63;
    const int j = blockIdx.x * 4 + w;
    const int tt = j >> 7, jt = j & 127;
    unsigned* row = (unsigned*)(St + (size_t)j * WIN);
    const int lo = max(jt, 256 - 128 * tt);
    const int hi = min(jt + 512, 4351 - 128 * tt);
    unsigned u[5]; float v[10];
    #pragma unroll
    for (int c = 0; c < 5; ++c) u[c] = row[l + 64 * c];
    float m = -3e38f;
    #pragma unroll
    for (int c = 0; c < 5; ++c) {
        int iw = 2 * (l + 64 * c);
        v[2 * c]     = (iw >= lo && iw <= hi)         ? bu2f((unsigned short)(u[c] & 0xffff)) : -3e38f;
        v[2 * c + 1] = (iw + 1 >= lo && iw + 1 <= hi) ? bu2f((unsigned short)(u[c] >> 16))    : -3e38f;
        m = fmaxf(m, fmaxf(v[2 * c], v[2 * c + 1]));
    }
    #pragma unroll
    for (int off = 32; off > 0; off >>= 1) m = fmaxf(m, __shfl_xor(m, off));
    float s = 0.f;
    #pragma unroll
    for (int c = 0; c < 10; ++c) {
        float e = (v[c] > -1e37f) ? __expf(v[c] - m) : 0.f;
        v[c] = e; s += e;
    }
    #pragma unroll
    for (int off = 32; off > 0; off >>= 1) s += __shfl_xor(s, off);
    const float inv = 1.f / s;
    #pragma unroll
    for (int c = 0; c < 5; ++c)
        row[l + 64 * c] = pk2(v[2 * c] * inv, v[2 * c + 1] * inv);
}

// ---------------- LayerNorm: O = LN(T (+X)) * g + b ----------------
__global__ __launch_bounds__(256) void ln_kernel(
    const bf16* __restrict__ T, const float* __restrict__ X,
    const float* __restrict__ g, const float* __restrict__ b, bf16* __restrict__ O)
{
    __shared__ float red1[4], red2[4];
    const int r = blockIdx.x, t = threadIdx.x, lane = t & 63, w = t >> 6;
    ushort4 tv = ((const ushort4*)(T + (size_t)r * DIM))[t];
    float v0 = bu2f(tv.x), v1 = bu2f(tv.y), v2 = bu2f(tv.z), v3 = bu2f(tv.w);
    if (X) {
        float4 xv = ((const float4*)(X + (size_t)r * DIM))[t];
        v0 += xv.x; v1 += xv.y; v2 += xv.z; v3 += xv.w;
    }
    float s = v0 + v1 + v2 + v3;
    #pragma unroll
    for (int off = 32; off > 0; off >>= 1) s += __shfl_xor(s, off);
    if (lane == 0) red1[w] = s;
    __syncthreads();
    float mu = (red1[0] + red1[1] + red1[2] + red1[3]) * (1.f / DIM);
    float d0 = v0 - mu, d1 = v1 - mu, d2 = v2 - mu, d3 = v3 - mu;
    float s2 = d0 * d0 + d1 * d1 + d2 * d2 + d3 * d3;
    #pragma unroll
    for (int off = 32; off > 0; off >>= 1) s2 += __shfl_xor(s2, off);
    if (lane == 0) red2[w] = s2;
    __syncthreads();
    float var = (red2[0] + red2[1] + red2[2] + red2[3]) * (1.f / DIM);
    float rstd = rsqrtf(var + 1e-3f);
    float4 gv = ((const float4*)g)[t];
    float4 bv = ((const float4*)b)[t];
    uint2 o;
    o.x = pk2(d0 * rstd * gv.x + bv.x, d1 * rstd * gv.y + bv.y);
    o.y = pk2(d2 * rstd * gv.z + bv.z, d3 * rstd * gv.w + bv.w);
    ((uint2*)(O + (size_t)r * DIM))[t] = o;
}

// ---------------- fused LN2 + final: out[r] = sigmoid(LN(T[r]).wkd + bkd) ----------------
__global__ __launch_bounds__(256) void lnfinal_kernel(
    const bf16* __restrict__ T, const float* __restrict__ g, const float* __restrict__ b,
    const float* __restrict__ wkd, const float* __restrict__ bkd, float* __restrict__ out)
{
    __shared__ float red1[4], red2[4], red3[4];
    const int r = blockIdx.x, t = threadIdx.x, lane = t & 63, w = t >> 6;
    ushort4 tv = ((const ushort4*)(T + (size_t)r * DIM))[t];
    float v0 = bu2f(tv.x), v1 = bu2f(tv.y), v2 = bu2f(tv.z), v3 = bu2f(tv.w);
    float s = v0 + v1 + v2 + v3;
    #pragma unroll
    for (int off = 32; off > 0; off >>= 1) s += __shfl_xor(s, off);
    if (lane == 0) red1[w] = s;
    __syncthreads();
    float mu = (red1[0] + red1[1] + red1[2] + red1[3]) * (1.f / DIM);
    float d0 = v0 - mu, d1 = v1 - mu, d2 = v2 - mu, d3 = v3 - mu;
    float s2 = d0 * d0 + d1 * d1 + d2 * d2 + d3 * d3;
    #pragma unroll
    for (int off = 32; off > 0; off >>= 1) s2 += __shfl_xor(s2, off);
    if (lane == 0) red2[w] = s2;
    __syncthreads();
    float var = (red2[0] + red2[1] + red2[2] + red2[3]) * (1.f / DIM);
    float rstd = rsqrtf(var + 1e-3f);
    float4 gv = ((const float4*)g)[t];
    float4 bv = ((const float4*)b)[t];
    float4 wv = ((const float4*)wkd)[t];
    float s3 = (d0 * rstd * gv.x + bv.x) * wv.x + (d1 * rstd * gv.y + bv.y) * wv.y
             + (d2 * rstd * gv.z + bv.z) * wv.z + (d3 * rstd * gv.w + bv.w) * wv.w;
    #pragma unroll
    for (int off = 32; off > 0; off >>= 1) s3 += __shfl_xor(s3, off);
    if (lane == 0) red3[w] = s3;
    __syncthreads();
    if (t == 0) {
        float tot = red3[0] + red3[1] + red3[2] + red3[3];
        out[r] = 1.f / (1.f + __expf(-(tot + bkd[0])));
    }
}

extern "C" void kernel_launch(void* const* d_in, const int* in_sizes, int n_in,
                              void* d_out, int out_size, void* d_ws, size_t ws_size,
                              hipStream_t stream) {
    const float* x    = (const float*)d_in[0];
    const float* wk   = (const float*)d_in[1];
    const float* wq   = (const float*)d_in[2];
    const float* wv   = (const float*)d_in[3];
    const float* wo   = (const float*)d_in[4];
    const float* wka  = (const float*)d_in[5];
    const float* bka  = (const float*)d_in[6];
    const float* wkd  = (const float*)d_in[7];
    const float* bkd  = (const float*)d_in[8];
    const float* g_y  = (const float*)d_in[9];
    const float* b_y  = (const float*)d_in[10];
    const float* g_ka = (const float*)d_in[11];
    const float* b_ka = (const float*)d_in[12];
    float* out = (float*)d_out;

    char* ws = (char*)d_ws;
    const size_t MB = 1u << 20;
    bf16* wkB  = (bf16*)(ws);              // 2 MB  wk (plain)
    bf16* wqB  = (bf16*)(ws + 2 * MB);     // 2 MB  wq (plain)
    bf16* wvB  = (bf16*)(ws + 4 * MB);     // 2 MB  wv (plain)
    bf16* woT  = (bf16*)(ws + 6 * MB);     // 2 MB  wo^T
    bf16* wkaT = (bf16*)(ws + 8 * MB);     // 2 MB  wka^T
    bf16* WqkT = (bf16*)(ws + 10 * MB);    // 2 MB  (wq@wk^T)^T = wk@wq^T
    bf16* wvoT = (bf16*)(ws + 12 * MB);    // 2 MB  (wv@wo)^T
    bf16* xb   = (bf16*)(ws + 14 * MB);    // 8 MB  x bf16
    bf16* Qh   = (bf16*)(ws + 22 * MB);    // 8 MB  x@Wqk
    bf16* Vtp  = (bf16*)(ws + 30 * MB);    // 9 MB  [1024][4608] (x@wvo)^T padded
    bf16* St   = (bf16*)(ws + 40 * MB);    // 5.25 MB [4096][640]
    bf16* fT   = (bf16*)(ws + 46 * MB);    // 8 MB  PV out = y@wo
    bf16* fL1  = (bf16*)(ws + 54 * MB);    // 8 MB  ln1 out
    bf16* fRel = (bf16*)(ws + 62 * MB);    // 8 MB  relu(.@wka+bka)

    zero_pads_kernel<<<512, 256, 0, stream>>>(Vtp);
    cast_x_kernel<<<NROW * DIM / 4 / 256, 256, 0, stream>>>(x, xb);
    WPtrs wp;
    wp.s[0] = wk;  wp.s[1] = wq;  wp.s[2] = wv;  wp.s[3] = wo;  wp.s[4] = wka;
    wp.d[0] = wkB; wp.d[1] = wqB; wp.d[2] = wvB; wp.d[3] = woT; wp.d[4] = wkaT;
    tcast_kernel<<<dim3(16, 16, 5), 256, 0, stream>>>(wp);

    // z=0: WqkT = wk@wq^T ; z=1: wvoT = wo^T@wv^T
    MiniPtrs mp;
    mp.A[0] = wkB; mp.Bt[0] = wqB; mp.C[0] = WqkT;
    mp.A[1] = woT; mp.Bt[1] = wvB; mp.C[1] = wvoT;
    gemm_mini<<<dim3(16, 16, 2), 256, 0, stream>>>(mp);

    // Qh = xb @ WqkT^T : [4096][1024]
    gemm_bt<128, 64><<<dim3(16, 32), 256, 0, stream>>>(
        xb, DIM, WqkT, DIM, Qh, DIM, DIM, 1.f, nullptr, 0, 0);
    // V'^T (padded) = wvoT @ xb^T : [1024][4096] into Vtp[:, 256:4352]
    gemm_bt<64, 128><<<dim3(32, 16), 256, 0, stream>>>(
        wvoT, DIM, xb, DIM, Vtp + 256, VTPW, DIM, 1.f, nullptr, 0, 0);

    score_gemm<<<dim3(WIN / 64, NROW / 128), 256, 0, stream>>>(Qh, xb, St);
    softmax_band<<<NROW / 4, 256, 0, stream>>>(St);
    // t = y@wo = St @ V'(band) : K=640 with per-j-tile Vtp column offset
    gemm_bt<64, 128><<<dim3(8, 64), 256, 0, stream>>>(
        St, WIN, Vtp, VTPW, fT, DIM, WIN, 1.f, nullptr, 0, 1);

    ln_kernel<<<NROW, 256, 0, stream>>>(fT, x, g_y, b_y, fL1);
    gemm_bt<128, 64><<<dim3(16, 32), 256, 0, stream>>>(
        fL1, DIM, wkaT, DIM, fRel, DIM, DIM, 1.f, bka, 1, 0);
    lnfinal_kernel<<<NROW, 256, 0, stream>>>(fRel, g_ka, b_ka, wkd, bkd, out);
}

// Round 10
// 124.408 us; speedup vs baseline: 1.6576x; 1.0488x over previous
//
#include <hip/hip_runtime.h>
#include <hip/hip_bf16.h>
#include <math.h>

typedef __hip_bfloat16 bf16;
typedef __attribute__((ext_vector_type(8))) short bf16x8;   // MFMA A/B frag (8 bf16)
typedef __attribute__((ext_vector_type(4))) float f32x4;    // MFMA C/D frag

#define NROW 4096
#define DIM  1024
#define APP  256
#define WIN  640          // band window per 128-row j-tile: 128 + 2*APP
#define VTPW 4608         // padded Vt width: 256 | 4096 | 256

__device__ __forceinline__ unsigned short f2bu(float f) {
    bf16 h = __float2bfloat16(f);
    return *reinterpret_cast<unsigned short*>(&h);
}
__device__ __forceinline__ float bu2f(unsigned short u) {
    bf16 h; *reinterpret_cast<unsigned short*>(&h) = u;
    return __bfloat162float(h);
}
__device__ __forceinline__ unsigned pk2(float a, float b) {
    return (unsigned)f2bu(a) | ((unsigned)f2bu(b) << 16);
}
__device__ __forceinline__ void gload_lds16(const void* g, void* l) {
    __builtin_amdgcn_global_load_lds(
        (const __attribute__((address_space(1))) unsigned int*)g,
        (__attribute__((address_space(3))) unsigned int*)l, 16, 0, 0);
}

// ================= fused prep: cast x | cast/transpose 5 weights | zero Vtp pads =================
// 1D grid of 3840 blocks:
//   [0,2048)    cast x -> xb (8 floats/thread)
//   [2048,3328) weight prep: z = (bid-2048)>>8; z<3 plain cast (wk,wq,wv); z>=3 transpose (wo,wka)
//   [3328,3840) zero pad strips of Vtp (cols 0..255 and 4352..4607)
struct PrepArgs { const float* x; bf16* xb; const float* srcw[5]; bf16* dstw[5]; bf16* Vtp; };
__global__ __launch_bounds__(256) void prep_kernel(PrepArgs p) {
    __shared__ float T[64][65];
    const int bid = blockIdx.x, t = threadIdx.x;
    if (bid < 2048) {
        size_t base = ((size_t)bid * 256 + t) * 8;
        float4 v0 = *(const float4*)(p.x + base);
        float4 v1 = *(const float4*)(p.x + base + 4);
        uint4 o;
        o.x = pk2(v0.x, v0.y); o.y = pk2(v0.z, v0.w);
        o.z = pk2(v1.x, v1.y); o.w = pk2(v1.z, v1.w);
        *(uint4*)(p.xb + base) = o;
        return;
    }
    if (bid < 3328) {
        int r = bid - 2048;
        const int z = r >> 8; r &= 255;
        const int r0 = (r & 15) * 64, c0 = (r >> 4) * 64;
        const float* in = p.srcw[z];
        bf16* out = p.dstw[z];
        if (z < 3) {
            #pragma unroll
            for (int c = 0; c < 4; ++c) {
                int row = (t >> 4) + c * 16, col = (t & 15) * 4;
                float4 v = *(const float4*)(in + (size_t)(r0 + row) * 1024 + c0 + col);
                uint2 o; o.x = pk2(v.x, v.y); o.y = pk2(v.z, v.w);
                *(uint2*)(out + (size_t)(r0 + row) * 1024 + c0 + col) = o;
            }
            return;
        }
        #pragma unroll
        for (int c = 0; c < 4; ++c) {
            int row = (t >> 4) + c * 16, col = (t & 15) * 4;
            float4 v = *(const float4*)(in + (size_t)(r0 + row) * 1024 + c0 + col);
            T[row][col] = v.x; T[row][col + 1] = v.y; T[row][col + 2] = v.z; T[row][col + 3] = v.w;
        }
        __syncthreads();
        #pragma unroll
        for (int c = 0; c < 4; ++c) {
            int orow = (t >> 4) + c * 16, ocol = (t & 15) * 4;
            uint2 o;
            o.x = pk2(T[ocol][orow], T[ocol + 1][orow]);
            o.y = pk2(T[ocol + 2][orow], T[ocol + 3][orow]);
            *(uint2*)(out + (size_t)(c0 + orow) * 1024 + r0 + ocol) = o;
        }
        return;
    }
    {
        int idx = (bid - 3328) * 256 + t;
        int row = idx >> 7;
        int c4  = idx & 127;
        int col = (c4 < 64) ? (c4 * 4) : (4352 + (c4 - 64) * 4);
        *(uint2*)(p.Vtp + (size_t)row * VTPW + col) = (uint2){0u, 0u};
    }
}

// ================= bf16 MFMA GEMM: C[M,N] = act(alpha*A@Bt^T + bias) =================
// A row-major [M,K] stride lda; Bt row-major [N,K] stride ldb; C stride ldc.
// pv!=0: Bt base += (m0>>7)*128 (banded PV: per-128-j-tile column offset into Vtp).
template <int BM, int BN>
__global__ __launch_bounds__(256) void gemm_bt(
    const bf16* __restrict__ A, int lda, const bf16* __restrict__ Bt, int ldb,
    bf16* __restrict__ C, int ldc, int K,
    float alpha, const float* __restrict__ bias, int relu, int pv)
{
    constexpr int WM = BM / 2, WN = BN / 2, AI = WM / 16, BJ = WN / 16;
    __shared__ bf16 As[BM * 64];
    __shared__ bf16 Bs[BN * 64];
    const int t = threadIdx.x, l = t & 63, w = t >> 6;
    const int wr = w >> 1, wc = w & 1;
    const int jl = l & 15, g = l >> 4;
    const int m0 = blockIdx.y * BM, n0 = blockIdx.x * BN;
    const bf16* Btb = pv ? (Bt + (size_t)(m0 >> 7) * 128) : Bt;

    f32x4 acc[AI][BJ];
    #pragma unroll
    for (int i = 0; i < AI; ++i)
        #pragma unroll
        for (int j = 0; j < BJ; ++j) acc[i][j] = (f32x4){0.f, 0.f, 0.f, 0.f};

    for (int kk = 0; kk < K; kk += 64) {
        __syncthreads();
        #pragma unroll
        for (int c = 0; c < BM / 32; ++c) {
            int q = t + c * 256;
            int row = q >> 3;
            int kel = ((q & 7) ^ (row & 7)) << 3;
            gload_lds16(A + (size_t)(m0 + row) * lda + kk + kel,
                        (char*)As + (c * 256 + w * 64) * 16);
        }
        #pragma unroll
        for (int c = 0; c < BN / 32; ++c) {
            int q = t + c * 256;
            int row = q >> 3;
            int kel = ((q & 7) ^ (row & 7)) << 3;
            gload_lds16(Btb + (size_t)(n0 + row) * ldb + kk + kel,
                        (char*)Bs + (c * 256 + w * 64) * 16);
        }
        __syncthreads();
        #pragma unroll
        for (int ks = 0; ks < 2; ++ks) {
            bf16x8 af[AI], bfr[BJ];
            #pragma unroll
            for (int i = 0; i < AI; ++i) {
                int ra = wr * WM + i * 16 + jl;
                af[i] = *(const bf16x8*)((char*)As + ra * 128 + ((ks * 64 + g * 16) ^ ((ra & 7) << 4)));
            }
            #pragma unroll
            for (int j = 0; j < BJ; ++j) {
                int rb = wc * WN + j * 16 + jl;
                bfr[j] = *(const bf16x8*)((char*)Bs + rb * 128 + ((ks * 64 + g * 16) ^ ((rb & 7) << 4)));
            }
            #pragma unroll
            for (int i = 0; i < AI; ++i)
                #pragma unroll
                for (int j = 0; j < BJ; ++j)
                    acc[i][j] = __builtin_amdgcn_mfma_f32_16x16x32_bf16(af[i], bfr[j], acc[i][j], 0, 0, 0);
        }
    }

    const int g4 = g * 4;
    #pragma unroll
    for (int j = 0; j < BJ; ++j) {
        int col = n0 + wc * WN + j * 16 + jl;
        float bv = bias ? bias[col] : 0.f;
        #pragma unroll
        for (int i = 0; i < AI; ++i) {
            int rowb = m0 + wr * WM + i * 16 + g4;
            #pragma unroll
            for (int r = 0; r < 4; ++r) {
                float vv = alpha * acc[i][j][r] + bv;
                if (relu) vv = fmaxf(vv, 0.f);
                C[(size_t)(rowb + r) * ldc + col] = __float2bfloat16(vv);
            }
        }
    }
}

// ================= two 1024^3 mini GEMMs (z=0: WqkT=wk@wq^T, z=1: wvoT=wo^T@wv^T) =================
struct MiniPtrs { const bf16* A[2]; const bf16* Bt[2]; bf16* C[2]; };
__global__ __launch_bounds__(256) void gemm_mini(MiniPtrs p) {
    constexpr int WM = 32, WN = 32, AI = 2, BJ = 2;
    __shared__ bf16 As[64 * 64];
    __shared__ bf16 Bs[64 * 64];
    const bf16* A  = p.A[blockIdx.z];
    const bf16* Bt = p.Bt[blockIdx.z];
    bf16* C        = p.C[blockIdx.z];
    const int t = threadIdx.x, l = t & 63, w = t >> 6;
    const int wr = w >> 1, wc = w & 1;
    const int jl = l & 15, g = l >> 4;
    const int m0 = blockIdx.y * 64, n0 = blockIdx.x * 64;

    f32x4 acc[AI][BJ];
    #pragma unroll
    for (int i = 0; i < AI; ++i)
        #pragma unroll
        for (int j = 0; j < BJ; ++j) acc[i][j] = (f32x4){0.f, 0.f, 0.f, 0.f};

    for (int kk = 0; kk < DIM; kk += 64) {
        __syncthreads();
        #pragma unroll
        for (int c = 0; c < 2; ++c) {
            int q = t + c * 256;
            int row = q >> 3;
            int kel = ((q & 7) ^ (row & 7)) << 3;
            gload_lds16(A + (size_t)(m0 + row) * DIM + kk + kel,
                        (char*)As + (c * 256 + w * 64) * 16);
            gload_lds16(Bt + (size_t)(n0 + row) * DIM + kk + kel,
                        (char*)Bs + (c * 256 + w * 64) * 16);
        }
        __syncthreads();
        #pragma unroll
        for (int ks = 0; ks < 2; ++ks) {
            bf16x8 af[AI], bfr[BJ];
            #pragma unroll
            for (int i = 0; i < AI; ++i) {
                int ra = wr * WM + i * 16 + jl;
                af[i] = *(const bf16x8*)((char*)As + ra * 128 + ((ks * 64 + g * 16) ^ ((ra & 7) << 4)));
            }
            #pragma unroll
            for (int j = 0; j < BJ; ++j) {
                int rb = wc * WN + j * 16 + jl;
                bfr[j] = *(const bf16x8*)((char*)Bs + rb * 128 + ((ks * 64 + g * 16) ^ ((rb & 7) << 4)));
            }
            #pragma unroll
            for (int i = 0; i < AI; ++i)
                #pragma unroll
                for (int j = 0; j < BJ; ++j)
                    acc[i][j] = __builtin_amdgcn_mfma_f32_16x16x32_bf16(af[i], bfr[j], acc[i][j], 0, 0, 0);
        }
    }

    const int g4 = g * 4;
    #pragma unroll
    for (int j = 0; j < BJ; ++j) {
        int col = n0 + wc * WN + j * 16 + jl;
        #pragma unroll
        for (int i = 0; i < AI; ++i) {
            int rowb = m0 + wr * WM + i * 16 + g4;
            #pragma unroll
            for (int r = 0; r < 4; ++r)
                C[(size_t)(rowb + r) * DIM + col] = __float2bfloat16(acc[i][j][r]);
        }
    }
}

// ================= banded score GEMM: St[j][iw] = 0.06 * Qh[win0+iw] . x[j] =================
__global__ __launch_bounds__(256) void score_gemm(const bf16* __restrict__ Qh,
                                                  const bf16* __restrict__ xb,
                                                  bf16* __restrict__ St)
{
    constexpr int WM = 32, WN = 64, AI = 2, BJ = 4;
    __shared__ bf16 As[64 * 64];
    __shared__ bf16 Bs[128 * 64];
    const int t = threadIdx.x, l = t & 63, w = t >> 6;
    const int wr = w >> 1, wc = w & 1;
    const int jl = l & 15, g = l >> 4;
    const int tt = blockIdx.y;              // j-tile 0..31
    const int c0 = blockIdx.x * 64;         // iw chunk base
    const int win0 = tt * 128 - APP;        // window start
    const bf16* Kb = xb + (size_t)tt * 128 * DIM;

    f32x4 acc[AI][BJ];
    #pragma unroll
    for (int i = 0; i < AI; ++i)
        #pragma unroll
        for (int j = 0; j < BJ; ++j) acc[i][j] = (f32x4){0.f, 0.f, 0.f, 0.f};

    for (int kk = 0; kk < DIM; kk += 64) {
        __syncthreads();
        #pragma unroll
        for (int c = 0; c < 2; ++c) {
            int q = t + c * 256;
            int row = q >> 3;
            int kel = ((q & 7) ^ (row & 7)) << 3;
            int rg = win0 + c0 + row;
            rg = min(max(rg, 0), NROW - 1);
            gload_lds16(Qh + (size_t)rg * DIM + kk + kel,
                        (char*)As + (c * 256 + w * 64) * 16);
        }
        #pragma unroll
        for (int c = 0; c < 4; ++c) {
            int q = t + c * 256;
            int row = q >> 3;
            int kel = ((q & 7) ^ (row & 7)) << 3;
            gload_lds16(Kb + (size_t)row * DIM + kk + kel,
                        (char*)Bs + (c * 256 + w * 64) * 16);
        }
        __syncthreads();
        #pragma unroll
        for (int ks = 0; ks < 2; ++ks) {
            bf16x8 af[AI], bfr[BJ];
            #pragma unroll
            for (int i = 0; i < AI; ++i) {
                int ra = wr * WM + i * 16 + jl;
                af[i] = *(const bf16x8*)((char*)As + ra * 128 + ((ks * 64 + g * 16) ^ ((ra & 7) << 4)));
            }
            #pragma unroll
            for (int j = 0; j < BJ; ++j) {
                int rb = wc * WN + j * 16 + jl;
                bfr[j] = *(const bf16x8*)((char*)Bs + rb * 128 + ((ks * 64 + g * 16) ^ ((rb & 7) << 4)));
            }
            #pragma unroll
            for (int i = 0; i < AI; ++i)
                #pragma unroll
                for (int j = 0; j < BJ; ++j)
                    acc[i][j] = __builtin_amdgcn_mfma_f32_16x16x32_bf16(af[i], bfr[j], acc[i][j], 0, 0, 0);
        }
    }

    const int g4 = g * 4;
    #pragma unroll
    for (int j = 0; j < BJ; ++j) {
        int coll = wc * WN + j * 16 + jl;
        bf16* strow = St + (size_t)(tt * 128 + coll) * WIN;
        #pragma unroll
        for (int i = 0; i < AI; ++i) {
            int iwb = c0 + wr * WM + i * 16 + g4;
            #pragma unroll
            for (int r = 0; r < 4; ++r)
                strow[iwb + r] = __float2bfloat16(0.06f * acc[i][j][r]);
        }
    }
}

// ================= masked row softmax over the 640-wide band window =================
__global__ __launch_bounds__(256) void softmax_band(bf16* __restrict__ St)
{
    const int w = threadIdx.x >> 6, l = threadIdx.x & 63;
    const int j = blockIdx.x * 4 + w;
    const int tt = j >> 7, jt = j & 127;
    unsigned* row = (unsigned*)(St + (size_t)j * WIN);
    const int lo = max(jt, 256 - 128 * tt);
    const int hi = min(jt + 512, 4351 - 128 * tt);
    unsigned u[5]; float v[10];
    #pragma unroll
    for (int c = 0; c < 5; ++c) u[c] = row[l + 64 * c];
    float m = -3e38f;
    #pragma unroll
    for (int c = 0; c < 5; ++c) {
        int iw = 2 * (l + 64 * c);
        v[2 * c]     = (iw >= lo && iw <= hi)         ? bu2f((unsigned short)(u[c] & 0xffff)) : -3e38f;
        v[2 * c + 1] = (iw + 1 >= lo && iw + 1 <= hi) ? bu2f((unsigned short)(u[c] >> 16))    : -3e38f;
        m = fmaxf(m, fmaxf(v[2 * c], v[2 * c + 1]));
    }
    #pragma unroll
    for (int off = 32; off > 0; off >>= 1) m = fmaxf(m, __shfl_xor(m, off));
    float s = 0.f;
    #pragma unroll
    for (int c = 0; c < 10; ++c) {
        float e = (v[c] > -1e37f) ? __expf(v[c] - m) : 0.f;
        v[c] = e; s += e;
    }
    #pragma unroll
    for (int off = 32; off > 0; off >>= 1) s += __shfl_xor(s, off);
    const float inv = 1.f / s;
    #pragma unroll
    for (int c = 0; c < 5; ++c)
        row[l + 64 * c] = pk2(v[2 * c] * inv, v[2 * c + 1] * inv);
}

// ================= LayerNorm: O = LN(T (+X)) * g + b =================
__global__ __launch_bounds__(256) void ln_kernel(
    const bf16* __restrict__ T, const float* __restrict__ X,
    const float* __restrict__ g, const float* __restrict__ b, bf16* __restrict__ O)
{
    __shared__ float red1[4], red2[4];
    const int r = blockIdx.x, t = threadIdx.x, lane = t & 63, w = t >> 6;
    ushort4 tv = ((const ushort4*)(T + (size_t)r * DIM))[t];
    float v0 = bu2f(tv.x), v1 = bu2f(tv.y), v2 = bu2f(tv.z), v3 = bu2f(tv.w);
    if (X) {
        float4 xv = ((const float4*)(X + (size_t)r * DIM))[t];
        v0 += xv.x; v1 += xv.y; v2 += xv.z; v3 += xv.w;
    }
    float s = v0 + v1 + v2 + v3;
    #pragma unroll
    for (int off = 32; off > 0; off >>= 1) s += __shfl_xor(s, off);
    if (lane == 0) red1[w] = s;
    __syncthreads();
    float mu = (red1[0] + red1[1] + red1[2] + red1[3]) * (1.f / DIM);
    float d0 = v0 - mu, d1 = v1 - mu, d2 = v2 - mu, d3 = v3 - mu;
    float s2 = d0 * d0 + d1 * d1 + d2 * d2 + d3 * d3;
    #pragma unroll
    for (int off = 32; off > 0; off >>= 1) s2 += __shfl_xor(s2, off);
    if (lane == 0) red2[w] = s2;
    __syncthreads();
    float var = (red2[0] + red2[1] + red2[2] + red2[3]) * (1.f / DIM);
    float rstd = rsqrtf(var + 1e-3f);
    float4 gv = ((const float4*)g)[t];
    float4 bv = ((const float4*)b)[t];
    uint2 o;
    o.x = pk2(d0 * rstd * gv.x + bv.x, d1 * rstd * gv.y + bv.y);
    o.y = pk2(d2 * rstd * gv.z + bv.z, d3 * rstd * gv.w + bv.w);
    ((uint2*)(O + (size_t)r * DIM))[t] = o;
}

// ================= fused LN2 + final: out[r] = sigmoid(LN(T[r]).wkd + bkd) =================
__global__ __launch_bounds__(256) void lnfinal_kernel(
    const bf16* __restrict__ T, const float* __restrict__ g, const float* __restrict__ b,
    const float* __restrict__ wkd, const float* __restrict__ bkd, float* __restrict__ out)
{
    __shared__ float red1[4], red2[4], red3[4];
    const int r = blockIdx.x, t = threadIdx.x, lane = t & 63, w = t >> 6;
    ushort4 tv = ((const ushort4*)(T + (size_t)r * DIM))[t];
    float v0 = bu2f(tv.x), v1 = bu2f(tv.y), v2 = bu2f(tv.z), v3 = bu2f(tv.w);
    float s = v0 + v1 + v2 + v3;
    #pragma unroll
    for (int off = 32; off > 0; off >>= 1) s += __shfl_xor(s, off);
    if (lane == 0) red1[w] = s;
    __syncthreads();
    float mu = (red1[0] + red1[1] + red1[2] + red1[3]) * (1.f / DIM);
    float d0 = v0 - mu, d1 = v1 - mu, d2 = v2 - mu, d3 = v3 - mu;
    float s2 = d0 * d0 + d1 * d1 + d2 * d2 + d3 * d3;
    #pragma unroll
    for (int off = 32; off > 0; off >>= 1) s2 += __shfl_xor(s2, off);
    if (lane == 0) red2[w] = s2;
    __syncthreads();
    float var = (red2[0] + red2[1] + red2[2] + red2[3]) * (1.f / DIM);
    float rstd = rsqrtf(var + 1e-3f);
    float4 gv = ((const float4*)g)[t];
    float4 bv = ((const float4*)b)[t];
    float4 wv = ((const float4*)wkd)[t];
    float s3 = (d0 * rstd * gv.x + bv.x) * wv.x + (d1 * rstd * gv.y + bv.y) * wv.y
             + (d2 * rstd * gv.z + bv.z) * wv.z + (d3 * rstd * gv.w + bv.w) * wv.w;
    #pragma unroll
    for (int off = 32; off > 0; off >>= 1) s3 += __shfl_xor(s3, off);
    if (lane == 0) red3[w] = s3;
    __syncthreads();
    if (t == 0) {
        float tot = red3[0] + red3[1] + red3[2] + red3[3];
        out[r] = 1.f / (1.f + __expf(-(tot + bkd[0])));
    }
}

extern "C" void kernel_launch(void* const* d_in, const int* in_sizes, int n_in,
                              void* d_out, int out_size, void* d_ws, size_t ws_size,
                              hipStream_t stream) {
    const float* x    = (const float*)d_in[0];
    const float* wk   = (const float*)d_in[1];
    const float* wq   = (const float*)d_in[2];
    const float* wv   = (const float*)d_in[3];
    const float* wo   = (const float*)d_in[4];
    const float* wka  = (const float*)d_in[5];
    const float* bka  = (const float*)d_in[6];
    const float* wkd  = (const float*)d_in[7];
    const float* bkd  = (const float*)d_in[8];
    const float* g_y  = (const float*)d_in[9];
    const float* b_y  = (const float*)d_in[10];
    const float* g_ka = (const float*)d_in[11];
    const float* b_ka = (const float*)d_in[12];
    float* out = (float*)d_out;

    char* ws = (char*)d_ws;
    const size_t MB = 1u << 20;
    bf16* wkB  = (bf16*)(ws);              // 2 MB  wk (plain)
    bf16* wqB  = (bf16*)(ws + 2 * MB);     // 2 MB  wq (plain)
    bf16* wvB  = (bf16*)(ws + 4 * MB);     // 2 MB  wv (plain)
    bf16* woT  = (bf16*)(ws + 6 * MB);     // 2 MB  wo^T
    bf16* wkaT = (bf16*)(ws + 8 * MB);     // 2 MB  wka^T
    bf16* WqkT = (bf16*)(ws + 10 * MB);    // 2 MB  (wq@wk^T)^T = wk@wq^T
    bf16* wvoT = (bf16*)(ws + 12 * MB);    // 2 MB  (wv@wo)^T
    bf16* xb   = (bf16*)(ws + 14 * MB);    // 8 MB  x bf16
    bf16* Qh   = (bf16*)(ws + 22 * MB);    // 8 MB  x@Wqk
    bf16* Vtp  = (bf16*)(ws + 30 * MB);    // 9 MB  [1024][4608] (x@wvo)^T padded
    bf16* St   = (bf16*)(ws + 40 * MB);    // 5.25 MB [4096][640]
    bf16* fT   = (bf16*)(ws + 46 * MB);    // 8 MB  PV out = y@wo
    bf16* fL1  = (bf16*)(ws + 54 * MB);    // 8 MB  ln1 out
    bf16* fRel = (bf16*)(ws + 62 * MB);    // 8 MB  relu(.@wka+bka)

    PrepArgs pa;
    pa.x = x; pa.xb = xb; pa.Vtp = Vtp;
    pa.srcw[0] = wk;  pa.srcw[1] = wq;  pa.srcw[2] = wv;  pa.srcw[3] = wo;  pa.srcw[4] = wka;
    pa.dstw[0] = wkB; pa.dstw[1] = wqB; pa.dstw[2] = wvB; pa.dstw[3] = woT; pa.dstw[4] = wkaT;
    prep_kernel<<<3840, 256, 0, stream>>>(pa);

    // z=0: WqkT = wk@wq^T ; z=1: wvoT = wo^T@wv^T
    MiniPtrs mp;
    mp.A[0] = wkB; mp.Bt[0] = wqB; mp.C[0] = WqkT;
    mp.A[1] = woT; mp.Bt[1] = wvB; mp.C[1] = wvoT;
    gemm_mini<<<dim3(16, 16, 2), 256, 0, stream>>>(mp);

    // Qh = xb @ WqkT^T : [4096][1024]
    gemm_bt<128, 64><<<dim3(16, 32), 256, 0, stream>>>(
        xb, DIM, WqkT, DIM, Qh, DIM, DIM, 1.f, nullptr, 0, 0);
    // V'^T (padded) = wvoT @ xb^T : [1024][4096] into Vtp[:, 256:4352]
    gemm_bt<64, 128><<<dim3(32, 16), 256, 0, stream>>>(
        wvoT, DIM, xb, DIM, Vtp + 256, VTPW, DIM, 1.f, nullptr, 0, 0);

    score_gemm<<<dim3(WIN / 64, NROW / 128), 256, 0, stream>>>(Qh, xb, St);
    softmax_band<<<NROW / 4, 256, 0, stream>>>(St);
    // t = y@wo = St @ V'(band) : K=640 with per-j-tile Vtp column offset
    gemm_bt<64, 128><<<dim3(8, 64), 256, 0, stream>>>(
        St, WIN, Vtp, VTPW, fT, DIM, WIN, 1.f, nullptr, 0, 1);

    ln_kernel<<<NROW, 256, 0, stream>>>(fT, x, g_y, b_y, fL1);
    gemm_bt<128, 64><<<dim3(16, 32), 256, 0, stream>>>(
        fL1, DIM, wkaT, DIM, fRel, DIM, DIM, 1.f, bka, 1, 0);
    lnfinal_kernel<<<NROW, 256, 0, stream>>>(fRel, g_ka, b_ka, wkd, bkd, out);
}

// Round 11
// 123.156 us; speedup vs baseline: 1.6744x; 1.0102x over previous
//
#include <hip/hip_runtime.h>
#include <hip/hip_bf16.h>
#include <math.h>

typedef __hip_bfloat16 bf16;
typedef __attribute__((ext_vector_type(8))) short bf16x8;   // MFMA A/B frag (8 bf16)
typedef __attribute__((ext_vector_type(4))) float f32x4;    // MFMA C/D frag

#define NROW 4096
#define DIM  1024
#define APP  256
#define WIN  640          // band window per 128-row j-tile: 128 + 2*APP
#define VTPW 4608         // padded Vt width: 256 | 4096 | 256
#define OLD  2048         // O = [Qh | V'] row stride

__device__ __forceinline__ unsigned short f2bu(float f) {
    bf16 h = __float2bfloat16(f);
    return *reinterpret_cast<unsigned short*>(&h);
}
__device__ __forceinline__ float bu2f(unsigned short u) {
    bf16 h; *reinterpret_cast<unsigned short*>(&h) = u;
    return __bfloat162float(h);
}
__device__ __forceinline__ unsigned pk2(float a, float b) {
    return (unsigned)f2bu(a) | ((unsigned)f2bu(b) << 16);
}
__device__ __forceinline__ void gload_lds16(const void* g, void* l) {
    __builtin_amdgcn_global_load_lds(
        (const __attribute__((address_space(1))) unsigned int*)g,
        (__attribute__((address_space(3))) unsigned int*)l, 16, 0, 0);
}

// ================= fused prep: cast x | cast/transpose 5 weights | zero Vtp pads =================
// 1D grid of 3840 blocks:
//   [0,2048)    cast x -> xb (8 floats/thread)
//   [2048,3328) weight prep: z = (bid-2048)>>8; z<3 plain cast (wk,wq,wv); z>=3 transpose (wo,wka)
//   [3328,3840) zero pad strips of Vtp (cols 0..255 and 4352..4607)
struct PrepArgs { const float* x; bf16* xb; const float* srcw[5]; bf16* dstw[5]; bf16* Vtp; };
__global__ __launch_bounds__(256) void prep_kernel(PrepArgs p) {
    __shared__ float T[64][65];
    const int bid = blockIdx.x, t = threadIdx.x;
    if (bid < 2048) {
        size_t base = ((size_t)bid * 256 + t) * 8;
        float4 v0 = *(const float4*)(p.x + base);
        float4 v1 = *(const float4*)(p.x + base + 4);
        uint4 o;
        o.x = pk2(v0.x, v0.y); o.y = pk2(v0.z, v0.w);
        o.z = pk2(v1.x, v1.y); o.w = pk2(v1.z, v1.w);
        *(uint4*)(p.xb + base) = o;
        return;
    }
    if (bid < 3328) {
        int r = bid - 2048;
        const int z = r >> 8; r &= 255;
        const int r0 = (r & 15) * 64, c0 = (r >> 4) * 64;
        const float* in = p.srcw[z];
        bf16* out = p.dstw[z];
        if (z < 3) {
            #pragma unroll
            for (int c = 0; c < 4; ++c) {
                int row = (t >> 4) + c * 16, col = (t & 15) * 4;
                float4 v = *(const float4*)(in + (size_t)(r0 + row) * 1024 + c0 + col);
                uint2 o; o.x = pk2(v.x, v.y); o.y = pk2(v.z, v.w);
                *(uint2*)(out + (size_t)(r0 + row) * 1024 + c0 + col) = o;
            }
            return;
        }
        #pragma unroll
        for (int c = 0; c < 4; ++c) {
            int row = (t >> 4) + c * 16, col = (t & 15) * 4;
            float4 v = *(const float4*)(in + (size_t)(r0 + row) * 1024 + c0 + col);
            T[row][col] = v.x; T[row][col + 1] = v.y; T[row][col + 2] = v.z; T[row][col + 3] = v.w;
        }
        __syncthreads();
        #pragma unroll
        for (int c = 0; c < 4; ++c) {
            int orow = (t >> 4) + c * 16, ocol = (t & 15) * 4;
            uint2 o;
            o.x = pk2(T[ocol][orow], T[ocol + 1][orow]);
            o.y = pk2(T[ocol + 2][orow], T[ocol + 3][orow]);
            *(uint2*)(out + (size_t)(c0 + orow) * 1024 + r0 + ocol) = o;
        }
        return;
    }
    {
        int idx = (bid - 3328) * 256 + t;
        int row = idx >> 7;
        int c4  = idx & 127;
        int col = (c4 < 64) ? (c4 * 4) : (4352 + (c4 - 64) * 4);
        *(uint2*)(p.Vtp + (size_t)row * VTPW + col) = (uint2){0u, 0u};
    }
}

// ================= bf16 MFMA GEMM: C[M,N] = act(alpha*A@Bt^T + bias) =================
// A row-major [M,K] stride lda; Bt row-major [N,K] stride ldb; C stride ldc.
// pv!=0: Bt base += (m0>>7)*128 (banded PV: per-128-j-tile column offset into Vtp).
template <int BM, int BN>
__global__ __launch_bounds__(256) void gemm_bt(
    const bf16* __restrict__ A, int lda, const bf16* __restrict__ Bt, int ldb,
    bf16* __restrict__ C, int ldc, int K,
    float alpha, const float* __restrict__ bias, int relu, int pv)
{
    constexpr int WM = BM / 2, WN = BN / 2, AI = WM / 16, BJ = WN / 16;
    __shared__ bf16 As[BM * 64];
    __shared__ bf16 Bs[BN * 64];
    const int t = threadIdx.x, l = t & 63, w = t >> 6;
    const int wr = w >> 1, wc = w & 1;
    const int jl = l & 15, g = l >> 4;
    const int m0 = blockIdx.y * BM, n0 = blockIdx.x * BN;
    const bf16* Btb = pv ? (Bt + (size_t)(m0 >> 7) * 128) : Bt;

    f32x4 acc[AI][BJ];
    #pragma unroll
    for (int i = 0; i < AI; ++i)
        #pragma unroll
        for (int j = 0; j < BJ; ++j) acc[i][j] = (f32x4){0.f, 0.f, 0.f, 0.f};

    for (int kk = 0; kk < K; kk += 64) {
        __syncthreads();
        #pragma unroll
        for (int c = 0; c < BM / 32; ++c) {
            int q = t + c * 256;
            int row = q >> 3;
            int kel = ((q & 7) ^ (row & 7)) << 3;
            gload_lds16(A + (size_t)(m0 + row) * lda + kk + kel,
                        (char*)As + (c * 256 + w * 64) * 16);
        }
        #pragma unroll
        for (int c = 0; c < BN / 32; ++c) {
            int q = t + c * 256;
            int row = q >> 3;
            int kel = ((q & 7) ^ (row & 7)) << 3;
            gload_lds16(Btb + (size_t)(n0 + row) * ldb + kk + kel,
                        (char*)Bs + (c * 256 + w * 64) * 16);
        }
        __syncthreads();
        #pragma unroll
        for (int ks = 0; ks < 2; ++ks) {
            bf16x8 af[AI], bfr[BJ];
            #pragma unroll
            for (int i = 0; i < AI; ++i) {
                int ra = wr * WM + i * 16 + jl;
                af[i] = *(const bf16x8*)((char*)As + ra * 128 + ((ks * 64 + g * 16) ^ ((ra & 7) << 4)));
            }
            #pragma unroll
            for (int j = 0; j < BJ; ++j) {
                int rb = wc * WN + j * 16 + jl;
                bfr[j] = *(const bf16x8*)((char*)Bs + rb * 128 + ((ks * 64 + g * 16) ^ ((rb & 7) << 4)));
            }
            #pragma unroll
            for (int i = 0; i < AI; ++i)
                #pragma unroll
                for (int j = 0; j < BJ; ++j)
                    acc[i][j] = __builtin_amdgcn_mfma_f32_16x16x32_bf16(af[i], bfr[j], acc[i][j], 0, 0, 0);
        }
    }

    const int g4 = g * 4;
    #pragma unroll
    for (int j = 0; j < BJ; ++j) {
        int col = n0 + wc * WN + j * 16 + jl;
        float bv = bias ? bias[col] : 0.f;
        #pragma unroll
        for (int i = 0; i < AI; ++i) {
            int rowb = m0 + wr * WM + i * 16 + g4;
            #pragma unroll
            for (int r = 0; r < 4; ++r) {
                float vv = alpha * acc[i][j][r] + bv;
                if (relu) vv = fmaxf(vv, 0.f);
                C[(size_t)(rowb + r) * ldc + col] = __float2bfloat16(vv);
            }
        }
    }
}

// ================= two 1024^3 mini GEMMs, 128x64 tiles (z=0: WqkT=wk@wq^T, z=1: wvoT=wo^T@wv^T) =================
struct MiniPtrs { const bf16* A[2]; const bf16* Bt[2]; bf16* C[2]; };
__global__ __launch_bounds__(256) void gemm_mini(MiniPtrs p) {
    constexpr int BM = 128, BN = 64, WM = 64, WN = 32, AI = 4, BJ = 2;
    __shared__ bf16 As[BM * 64];
    __shared__ bf16 Bs[BN * 64];
    const bf16* A  = p.A[blockIdx.z];
    const bf16* Bt = p.Bt[blockIdx.z];
    bf16* C        = p.C[blockIdx.z];
    const int t = threadIdx.x, l = t & 63, w = t >> 6;
    const int wr = w >> 1, wc = w & 1;
    const int jl = l & 15, g = l >> 4;
    const int m0 = blockIdx.y * BM, n0 = blockIdx.x * BN;

    f32x4 acc[AI][BJ];
    #pragma unroll
    for (int i = 0; i < AI; ++i)
        #pragma unroll
        for (int j = 0; j < BJ; ++j) acc[i][j] = (f32x4){0.f, 0.f, 0.f, 0.f};

    for (int kk = 0; kk < DIM; kk += 64) {
        __syncthreads();
        #pragma unroll
        for (int c = 0; c < BM / 32; ++c) {
            int q = t + c * 256;
            int row = q >> 3;
            int kel = ((q & 7) ^ (row & 7)) << 3;
            gload_lds16(A + (size_t)(m0 + row) * DIM + kk + kel,
                        (char*)As + (c * 256 + w * 64) * 16);
        }
        #pragma unroll
        for (int c = 0; c < BN / 32; ++c) {
            int q = t + c * 256;
            int row = q >> 3;
            int kel = ((q & 7) ^ (row & 7)) << 3;
            gload_lds16(Bt + (size_t)(n0 + row) * DIM + kk + kel,
                        (char*)Bs + (c * 256 + w * 64) * 16);
        }
        __syncthreads();
        #pragma unroll
        for (int ks = 0; ks < 2; ++ks) {
            bf16x8 af[AI], bfr[BJ];
            #pragma unroll
            for (int i = 0; i < AI; ++i) {
                int ra = wr * WM + i * 16 + jl;
                af[i] = *(const bf16x8*)((char*)As + ra * 128 + ((ks * 64 + g * 16) ^ ((ra & 7) << 4)));
            }
            #pragma unroll
            for (int j = 0; j < BJ; ++j) {
                int rb = wc * WN + j * 16 + jl;
                bfr[j] = *(const bf16x8*)((char*)Bs + rb * 128 + ((ks * 64 + g * 16) ^ ((rb & 7) << 4)));
            }
            #pragma unroll
            for (int i = 0; i < AI; ++i)
                #pragma unroll
                for (int j = 0; j < BJ; ++j)
                    acc[i][j] = __builtin_amdgcn_mfma_f32_16x16x32_bf16(af[i], bfr[j], acc[i][j], 0, 0, 0);
        }
    }

    const int g4 = g * 4;
    #pragma unroll
    for (int j = 0; j < BJ; ++j) {
        int col = n0 + wc * WN + j * 16 + jl;
        #pragma unroll
        for (int i = 0; i < AI; ++i) {
            int rowb = m0 + wr * WM + i * 16 + g4;
            #pragma unroll
            for (int r = 0; r < 4; ++r)
                C[(size_t)(rowb + r) * DIM + col] = __float2bfloat16(acc[i][j][r]);
        }
    }
}

// ================= transpose V' (cols 1024..2047 of O) into padded Vtp =================
// Vtp[d][256 + j] = O[j][1024 + d]. Grid (64 j-tiles, 16 d-tiles), 64x64 tiles.
__global__ __launch_bounds__(256) void tpad_kernel(const bf16* __restrict__ O,
                                                   bf16* __restrict__ Vtp)
{
    __shared__ unsigned short T[64][65];
    const int t = threadIdx.x;
    const int j0 = blockIdx.x * 64, d0 = blockIdx.y * 64;
    #pragma unroll
    for (int c = 0; c < 4; ++c) {
        int row = (t >> 4) + c * 16, col = (t & 15) * 4;   // row=j_local, col=d_local
        uint2 v = *(const uint2*)(O + (size_t)(j0 + row) * OLD + 1024 + d0 + col);
        T[row][col]     = (unsigned short)(v.x & 0xffff);
        T[row][col + 1] = (unsigned short)(v.x >> 16);
        T[row][col + 2] = (unsigned short)(v.y & 0xffff);
        T[row][col + 3] = (unsigned short)(v.y >> 16);
    }
    __syncthreads();
    #pragma unroll
    for (int c = 0; c < 4; ++c) {
        int orow = (t >> 4) + c * 16, ocol = (t & 15) * 4; // orow=d_local, ocol=j_local
        uint2 o;
        o.x = (unsigned)T[ocol][orow]     | ((unsigned)T[ocol + 1][orow] << 16);
        o.y = (unsigned)T[ocol + 2][orow] | ((unsigned)T[ocol + 3][orow] << 16);
        *(uint2*)(Vtp + (size_t)(d0 + orow) * VTPW + 256 + j0 + ocol) = o;
    }
}

// ================= banded score GEMM: St[j][iw] = 0.06 * Qh[win0+iw] . x[j] =================
// Qh = cols 0..1023 of O (lda = OLD).
__global__ __launch_bounds__(256) void score_gemm(const bf16* __restrict__ Qh,
                                                  const bf16* __restrict__ xb,
                                                  bf16* __restrict__ St)
{
    constexpr int WM = 32, WN = 64, AI = 2, BJ = 4;
    __shared__ bf16 As[64 * 64];
    __shared__ bf16 Bs[128 * 64];
    const int t = threadIdx.x, l = t & 63, w = t >> 6;
    const int wr = w >> 1, wc = w & 1;
    const int jl = l & 15, g = l >> 4;
    const int tt = blockIdx.y;              // j-tile 0..31
    const int c0 = blockIdx.x * 64;         // iw chunk base
    const int win0 = tt * 128 - APP;        // window start
    const bf16* Kb = xb + (size_t)tt * 128 * DIM;

    f32x4 acc[AI][BJ];
    #pragma unroll
    for (int i = 0; i < AI; ++i)
        #pragma unroll
        for (int j = 0; j < BJ; ++j) acc[i][j] = (f32x4){0.f, 0.f, 0.f, 0.f};

    for (int kk = 0; kk < DIM; kk += 64) {
        __syncthreads();
        #pragma unroll
        for (int c = 0; c < 2; ++c) {
            int q = t + c * 256;
            int row = q >> 3;
            int kel = ((q & 7) ^ (row & 7)) << 3;
            int rg = win0 + c0 + row;
            rg = min(max(rg, 0), NROW - 1);
            gload_lds16(Qh + (size_t)rg * OLD + kk + kel,
                        (char*)As + (c * 256 + w * 64) * 16);
        }
        #pragma unroll
        for (int c = 0; c < 4; ++c) {
            int q = t + c * 256;
            int row = q >> 3;
            int kel = ((q & 7) ^ (row & 7)) << 3;
            gload_lds16(Kb + (size_t)row * DIM + kk + kel,
                        (char*)Bs + (c * 256 + w * 64) * 16);
        }
        __syncthreads();
        #pragma unroll
        for (int ks = 0; ks < 2; ++ks) {
            bf16x8 af[AI], bfr[BJ];
            #pragma unroll
            for (int i = 0; i < AI; ++i) {
                int ra = wr * WM + i * 16 + jl;
                af[i] = *(const bf16x8*)((char*)As + ra * 128 + ((ks * 64 + g * 16) ^ ((ra & 7) << 4)));
            }
            #pragma unroll
            for (int j = 0; j < BJ; ++j) {
                int rb = wc * WN + j * 16 + jl;
                bfr[j] = *(const bf16x8*)((char*)Bs + rb * 128 + ((ks * 64 + g * 16) ^ ((rb & 7) << 4)));
            }
            #pragma unroll
            for (int i = 0; i < AI; ++i)
                #pragma unroll
                for (int j = 0; j < BJ; ++j)
                    acc[i][j] = __builtin_amdgcn_mfma_f32_16x16x32_bf16(af[i], bfr[j], acc[i][j], 0, 0, 0);
        }
    }

    const int g4 = g * 4;
    #pragma unroll
    for (int j = 0; j < BJ; ++j) {
        int coll = wc * WN + j * 16 + jl;
        bf16* strow = St + (size_t)(tt * 128 + coll) * WIN;
        #pragma unroll
        for (int i = 0; i < AI; ++i) {
            int iwb = c0 + wr * WM + i * 16 + g4;
            #pragma unroll
            for (int r = 0; r < 4; ++r)
                strow[iwb + r] = __float2bfloat16(0.06f * acc[i][j][r]);
        }
    }
}

// ================= masked row softmax over the 640-wide band window =================
__global__ __launch_bounds__(256) void softmax_band(bf16* __restrict__ St)
{
    const int w = threadIdx.x >> 6, l = threadIdx.x & 63;
    const int j = blockIdx.x * 4 + w;
    const int tt = j >> 7, jt = j & 127;
    unsigned* row = (unsigned*)(St + (size_t)j * WIN);
    const int lo = max(jt, 256 - 128 * tt);
    const int hi = min(jt + 512, 4351 - 128 * tt);
    unsigned u[5]; float v[10];
    #pragma unroll
    for (int c = 0; c < 5; ++c) u[c] = row[l + 64 * c];
    float m = -3e38f;
    #pragma unroll
    for (int c = 0; c < 5; ++c) {
        int iw = 2 * (l + 64 * c);
        v[2 * c]     = (iw >= lo && iw <= hi)         ? bu2f((unsigned short)(u[c] & 0xffff)) : -3e38f;
        v[2 * c + 1] = (iw + 1 >= lo && iw + 1 <= hi) ? bu2f((unsigned short)(u[c] >> 16))    : -3e38f;
        m = fmaxf(m, fmaxf(v[2 * c], v[2 * c + 1]));
    }
    #pragma unroll
    for (int off = 32; off > 0; off >>= 1) m = fmaxf(m, __shfl_xor(m, off));
    float s = 0.f;
    #pragma unroll
    for (int c = 0; c < 10; ++c) {
        float e = (v[c] > -1e37f) ? __expf(v[c] - m) : 0.f;
        v[c] = e; s += e;
    }
    #pragma unroll
    for (int off = 32; off > 0; off >>= 1) s += __shfl_xor(s, off);
    const float inv = 1.f / s;
    #pragma unroll
    for (int c = 0; c < 5; ++c)
        row[l + 64 * c] = pk2(v[2 * c] * inv, v[2 * c + 1] * inv);
}

// ================= LayerNorm: O = LN(T + Xb) * g + b  (Xb bf16 residual, may be null) =================
__global__ __launch_bounds__(256) void ln_kernel(
    const bf16* __restrict__ T, const bf16* __restrict__ Xb,
    const float* __restrict__ g, const float* __restrict__ b, bf16* __restrict__ O)
{
    __shared__ float red1[4], red2[4];
    const int r = blockIdx.x, t = threadIdx.x, lane = t & 63, w = t >> 6;
    ushort4 tv = ((const ushort4*)(T + (size_t)r * DIM))[t];
    float v0 = bu2f(tv.x), v1 = bu2f(tv.y), v2 = bu2f(tv.z), v3 = bu2f(tv.w);
    if (Xb) {
        ushort4 xv = ((const ushort4*)(Xb + (size_t)r * DIM))[t];
        v0 += bu2f(xv.x); v1 += bu2f(xv.y); v2 += bu2f(xv.z); v3 += bu2f(xv.w);
    }
    float s = v0 + v1 + v2 + v3;
    #pragma unroll
    for (int off = 32; off > 0; off >>= 1) s += __shfl_xor(s, off);
    if (lane == 0) red1[w] = s;
    __syncthreads();
    float mu = (red1[0] + red1[1] + red1[2] + red1[3]) * (1.f / DIM);
    float d0 = v0 - mu, d1 = v1 - mu, d2 = v2 - mu, d3 = v3 - mu;
    float s2 = d0 * d0 + d1 * d1 + d2 * d2 + d3 * d3;
    #pragma unroll
    for (int off = 32; off > 0; off >>= 1) s2 += __shfl_xor(s2, off);
    if (lane == 0) red2[w] = s2;
    __syncthreads();
    float var = (red2[0] + red2[1] + red2[2] + red2[3]) * (1.f / DIM);
    float rstd = rsqrtf(var + 1e-3f);
    float4 gv = ((const float4*)g)[t];
    float4 bv = ((const float4*)b)[t];
    uint2 o;
    o.x = pk2(d0 * rstd * gv.x + bv.x, d1 * rstd * gv.y + bv.y);
    o.y = pk2(d2 * rstd * gv.z + bv.z, d3 * rstd * gv.w + bv.w);
    ((uint2*)(O + (size_t)r * DIM))[t] = o;
}

// ================= fused LN2 + final: out[r] = sigmoid(LN(T[r]).wkd + bkd) =================
__global__ __launch_bounds__(256) void lnfinal_kernel(
    const bf16* __restrict__ T, const float* __restrict__ g, const float* __restrict__ b,
    const float* __restrict__ wkd, const float* __restrict__ bkd, float* __restrict__ out)
{
    __shared__ float red1[4], red2[4], red3[4];
    const int r = blockIdx.x, t = threadIdx.x, lane = t & 63, w = t >> 6;
    ushort4 tv = ((const ushort4*)(T + (size_t)r * DIM))[t];
    float v0 = bu2f(tv.x), v1 = bu2f(tv.y), v2 = bu2f(tv.z), v3 = bu2f(tv.w);
    float s = v0 + v1 + v2 + v3;
    #pragma unroll
    for (int off = 32; off > 0; off >>= 1) s += __shfl_xor(s, off);
    if (lane == 0) red1[w] = s;
    __syncthreads();
    float mu = (red1[0] + red1[1] + red1[2] + red1[3]) * (1.f / DIM);
    float d0 = v0 - mu, d1 = v1 - mu, d2 = v2 - mu, d3 = v3 - mu;
    float s2 = d0 * d0 + d1 * d1 + d2 * d2 + d3 * d3;
    #pragma unroll
    for (int off = 32; off > 0; off >>= 1) s2 += __shfl_xor(s2, off);
    if (lane == 0) red2[w] = s2;
    __syncthreads();
    float var = (red2[0] + red2[1] + red2[2] + red2[3]) * (1.f / DIM);
    float rstd = rsqrtf(var + 1e-3f);
    float4 gv = ((const float4*)g)[t];
    float4 bv = ((const float4*)b)[t];
    float4 wv = ((const float4*)wkd)[t];
    float s3 = (d0 * rstd * gv.x + bv.x) * wv.x + (d1 * rstd * gv.y + bv.y) * wv.y
             + (d2 * rstd * gv.z + bv.z) * wv.z + (d3 * rstd * gv.w + bv.w) * wv.w;
    #pragma unroll
    for (int off = 32; off > 0; off >>= 1) s3 += __shfl_xor(s3, off);
    if (lane == 0) red3[w] = s3;
    __syncthreads();
    if (t == 0) {
        float tot = red3[0] + red3[1] + red3[2] + red3[3];
        out[r] = 1.f / (1.f + __expf(-(tot + bkd[0])));
    }
}

extern "C" void kernel_launch(void* const* d_in, const int* in_sizes, int n_in,
                              void* d_out, int out_size, void* d_ws, size_t ws_size,
                              hipStream_t stream) {
    const float* x    = (const float*)d_in[0];
    const float* wk   = (const float*)d_in[1];
    const float* wq   = (const float*)d_in[2];
    const float* wv   = (const float*)d_in[3];
    const float* wo   = (const float*)d_in[4];
    const float* wka  = (const float*)d_in[5];
    const float* bka  = (const float*)d_in[6];
    const float* wkd  = (const float*)d_in[7];
    const float* bkd  = (const float*)d_in[8];
    const float* g_y  = (const float*)d_in[9];
    const float* b_y  = (const float*)d_in[10];
    const float* g_ka = (const float*)d_in[11];
    const float* b_ka = (const float*)d_in[12];
    float* out = (float*)d_out;

    char* ws = (char*)d_ws;
    const size_t MB = 1u << 20;
    bf16* wkB  = (bf16*)(ws);              // 2 MB  wk (plain)
    bf16* wqB  = (bf16*)(ws + 2 * MB);     // 2 MB  wq (plain)
    bf16* wvB  = (bf16*)(ws + 4 * MB);     // 2 MB  wv (plain)
    bf16* woT  = (bf16*)(ws + 6 * MB);     // 2 MB  wo^T
    bf16* wkaT = (bf16*)(ws + 8 * MB);     // 2 MB  wka^T
    bf16* WqkT = (bf16*)(ws + 10 * MB);    // 2 MB  wk@wq^T  (rows 0..1023 of concat Bt)
    bf16* wvoT = (bf16*)(ws + 12 * MB);    // 2 MB  (wv@wo)^T (rows 1024..2047, contiguous!)
    bf16* xb   = (bf16*)(ws + 14 * MB);    // 8 MB  x bf16
    bf16* Obuf = (bf16*)(ws + 22 * MB);    // 16 MB [4096][2048] = [Qh | V']
    bf16* Vtp  = (bf16*)(ws + 38 * MB);    // 9 MB  [1024][4608] V'^T padded
    bf16* St   = (bf16*)(ws + 47 * MB);    // 5.25 MB [4096][640]
    bf16* fT   = (bf16*)(ws + 53 * MB);    // 8 MB  PV out = y@wo
    bf16* fL1  = (bf16*)(ws + 61 * MB);    // 8 MB  ln1 out
    bf16* fRel = (bf16*)(ws + 69 * MB);    // 8 MB  relu(.@wka+bka)

    PrepArgs pa;
    pa.x = x; pa.xb = xb; pa.Vtp = Vtp;
    pa.srcw[0] = wk;  pa.srcw[1] = wq;  pa.srcw[2] = wv;  pa.srcw[3] = wo;  pa.srcw[4] = wka;
    pa.dstw[0] = wkB; pa.dstw[1] = wqB; pa.dstw[2] = wvB; pa.dstw[3] = woT; pa.dstw[4] = wkaT;
    prep_kernel<<<3840, 256, 0, stream>>>(pa);

    // z=0: WqkT = wk@wq^T ; z=1: wvoT = wo^T@wv^T  (128x64 tiles, one launch)
    MiniPtrs mp;
    mp.A[0] = wkB; mp.Bt[0] = wqB; mp.C[0] = WqkT;
    mp.A[1] = woT; mp.Bt[1] = wvB; mp.C[1] = wvoT;
    gemm_mini<<<dim3(16, 8, 2), 256, 0, stream>>>(mp);

    // O = xb @ [WqkT; wvoT]^T : [4096][2048] = [Qh | V']   (single fat GEMM)
    gemm_bt<128, 128><<<dim3(16, 32), 256, 0, stream>>>(
        xb, DIM, WqkT, DIM, Obuf, OLD, DIM, 1.f, nullptr, 0, 0);
    // Vtp[d][256+j] = V'[j][d]
    tpad_kernel<<<dim3(64, 16), 256, 0, stream>>>(Obuf, Vtp);

    score_gemm<<<dim3(WIN / 64, NROW / 128), 256, 0, stream>>>(Obuf, xb, St);
    softmax_band<<<NROW / 4, 256, 0, stream>>>(St);
    // t = y@wo = St @ V'(band) : K=640 with per-j-tile Vtp column offset
    gemm_bt<64, 128><<<dim3(8, 64), 256, 0, stream>>>(
        St, WIN, Vtp, VTPW, fT, DIM, WIN, 1.f, nullptr, 0, 1);

    ln_kernel<<<NROW, 256, 0, stream>>>(fT, xb, g_y, b_y, fL1);
    gemm_bt<128, 64><<<dim3(16, 32), 256, 0, stream>>>(
        fL1, DIM, wkaT, DIM, fRel, DIM, DIM, 1.f, bka, 1, 0);
    lnfinal_kernel<<<NROW, 256, 0, stream>>>(fRel, g_ka, b_ka, wkd, bkd, out);
}